// Round 3
// baseline (2089.212 us; speedup 1.0000x reference)
//
#include <hip/hip_runtime.h>
#include <math.h>

#define TT 4096
#define AA 4
#define NN 16384
#define QBQ 32
#define KBK 128
#define SS 512
#define HH 4
#define DKD 32
#define CAC 128
#define CPC 16
#define CTC 384

#define EPI_PLAIN 0
#define EPI_SIG   1
#define EPI_ADA   2
#define EPI_RELU  3

__device__ __forceinline__ float sig_(float x) { return 1.0f / (1.0f + __expf(-x)); }

// ---------------------------------------------------------------------------
// K1: per-atom conditioning: act (=qsc, init qact), qn = LN(act) (unweighted),
//     rq = relu(act)@w_s2p_row, rk = relu(act)@w_s2p_col
// ---------------------------------------------------------------------------
__global__ __launch_bounds__(128) void k_atom_cond(
    const float* __restrict__ pos, const float* __restrict__ msk,
    const int* __restrict__ elem, const float* __restrict__ chg,
    const int* __restrict__ chars,
    const float* __restrict__ w_pos, const float* __restrict__ w_msk,
    const float* __restrict__ w_elem, const float* __restrict__ w_chg,
    const float* __restrict__ w_name,
    const float* __restrict__ w_row, const float* __restrict__ w_col,
    float* __restrict__ qsc, float* __restrict__ qact, float* __restrict__ qn,
    float* __restrict__ rq, float* __restrict__ rk)
{
    const int n = blockIdx.x, c = threadIdx.x;
    const float p0 = pos[n*3+0], p1 = pos[n*3+1], p2 = pos[n*3+2];
    const float m = msk[n];
    const int   el = elem[n];
    const float ach = asinhf(chg[n]);
    const int c0 = chars[n*4+0], c1 = chars[n*4+1], c2 = chars[n*4+2], c3 = chars[n*4+3];

    float a = p0*w_pos[c] + p1*w_pos[CAC+c] + p2*w_pos[2*CAC+c]
            + m*w_msk[c] + w_elem[el*CAC+c] + ach*w_chg[c]
            + w_name[(c0      )*CAC+c] + w_name[( 64+c1)*CAC+c]
            + w_name[(128+c2)*CAC+c] + w_name[(192+c3)*CAC+c];
    a *= m;

    const size_t base = (size_t)n*CAC + c;
    qsc[base] = a; qact[base] = a;

    __shared__ float red[128];
    __shared__ float sh[128];
    red[c] = a; __syncthreads();
    for (int off = 64; off > 0; off >>= 1) { if (c < off) red[c] += red[c+off]; __syncthreads(); }
    const float mu = red[0] * (1.0f/128.0f);
    __syncthreads();
    const float d = a - mu;
    red[c] = d*d; __syncthreads();
    for (int off = 64; off > 0; off >>= 1) { if (c < off) red[c] += red[c+off]; __syncthreads(); }
    const float var = red[0] * (1.0f/128.0f);
    qn[base] = d * rsqrtf(var + 1e-5f);
    __syncthreads();
    sh[c] = fmaxf(a, 0.0f);
    __syncthreads();
    if (c < 32) {
        const float* w = (c < 16) ? w_row : w_col;
        const int cc = c & 15;
        float acc = 0.0f;
        #pragma unroll 8
        for (int r = 0; r < 128; ++r) acc += sh[r] * w[r*CPC + cc];
        if (c < 16) rq[(size_t)n*CPC + cc] = acc;
        else        rk[(size_t)n*CPC + cc] = acc;
    }
}

// ---------------------------------------------------------------------------
// K2: pair conditioning + 3-layer MLP residual; one thread per (s,q,k).
//     Optionally also computes pl = LN(pair)@w_pair_logits for npl blocks
//     (layout [i][s][h][q][kb]) while pair values are still in registers.
// ---------------------------------------------------------------------------
__global__ __launch_bounds__(256) void k_pair(
    const float* __restrict__ pos, const int* __restrict__ uid,
    const float* __restrict__ rq, const float* __restrict__ rk,
    const float* __restrict__ w_ofs, const float* __restrict__ w_dist,
    const float* __restrict__ w_pm,
    const float* __restrict__ mlp1, const float* __restrict__ mlp2,
    const float* __restrict__ mlp3,
    const float* __restrict__ wln, const float* __restrict__ wpl,
    float* __restrict__ pair, float* __restrict__ pl, int npl)
{
    __shared__ float sm1[256], sm2[256], sm3[256], sofs[48], sdist[16], smask[16];
    __shared__ float swln[16], swpl[192];
    const int tid = threadIdx.x;
    sm1[tid] = mlp1[tid]; sm2[tid] = mlp2[tid]; sm3[tid] = mlp3[tid];
    if (tid < 48) sofs[tid] = w_ofs[tid];
    if (tid < 16) { sdist[tid] = w_dist[tid]; smask[tid] = w_pm[tid]; swln[tid] = wln[tid]; }
    if (tid < 192) swpl[tid] = wpl[tid];
    __syncthreads();

    const int gid = blockIdx.x*256 + tid;
    const int s = gid >> 12;
    const int rem = gid & 4095;
    const int q = rem >> 7, kk = rem & 127;
    const int n = s*QBQ + q;
    int kidx = s*QBQ - 48 + kk; kidx = max(0, min(NN-1, kidx));

    const float v = (uid[n] == uid[kidx]) ? 1.0f : 0.0f;
    const float o0 = pos[n*3+0]-pos[kidx*3+0];
    const float o1 = pos[n*3+1]-pos[kidx*3+1];
    const float o2 = pos[n*3+2]-pos[kidx*3+2];
    const float sq = o0*o0 + o1*o1 + o2*o2;
    const float inv = 1.0f/(1.0f + sq);

    const float* rqp = rq + (size_t)n*CPC;
    const float* rkp = rk + (size_t)kidx*CPC;

    float p[16], t1[16], t2[16];
    #pragma unroll
    for (int j = 0; j < 16; ++j)
        p[j] = v*(o0*sofs[j] + o1*sofs[16+j] + o2*sofs[32+j] + inv*sdist[j] + smask[j])
             + rqp[j] + rkp[j];
    #pragma unroll
    for (int j = 0; j < 16; ++j) {
        float acc = 0.0f;
        #pragma unroll
        for (int r = 0; r < 16; ++r) acc += fmaxf(p[r], 0.0f) * sm1[r*16+j];
        t1[j] = acc;
    }
    #pragma unroll
    for (int j = 0; j < 16; ++j) {
        float acc = 0.0f;
        #pragma unroll
        for (int r = 0; r < 16; ++r) acc += fmaxf(t1[r], 0.0f) * sm2[r*16+j];
        t2[j] = acc;
    }
    #pragma unroll
    for (int j = 0; j < 16; ++j) {
        float acc = 0.0f;
        #pragma unroll
        for (int r = 0; r < 16; ++r) acc += fmaxf(t2[r], 0.0f) * sm3[r*16+j];
        t1[j] = p[j] + acc;
    }
    float* op = pair + (size_t)gid*CPC;
    #pragma unroll
    for (int j = 0; j < 4; ++j)
        *(float4*)(op + j*4) = make_float4(t1[j*4], t1[j*4+1], t1[j*4+2], t1[j*4+3]);

    if (npl > 0) {
        // LN over the 16 pair channels, then project to npl*4 logit planes
        float sm = 0.0f;
        #pragma unroll
        for (int j = 0; j < 16; ++j) sm += t1[j];
        const float mu = sm * (1.0f/16.0f);
        float vq = 0.0f;
        #pragma unroll
        for (int j = 0; j < 16; ++j) { const float dd = t1[j]-mu; vq += dd*dd; }
        const float rs = rsqrtf(vq*(1.0f/16.0f) + 1e-5f);
        float xn[16];
        #pragma unroll
        for (int j = 0; j < 16; ++j) xn[j] = (t1[j]-mu)*rs*swln[j];
        for (int i = 0; i < npl; ++i) {
            #pragma unroll
            for (int h = 0; h < 4; ++h) {
                float acc = 0.0f;
                #pragma unroll
                for (int j = 0; j < 16; ++j) acc += xn[j] * swpl[j*12 + i*4 + h];
                pl[((((size_t)i*SS + s)*HH + h)*QBQ + q)*KBK + kk] = acc;
            }
        }
    }
}

// ---------------------------------------------------------------------------
// K2b: standalone pair->pl for one transformer block (PER-BLOCK ws mode)
// ---------------------------------------------------------------------------
__global__ __launch_bounds__(256) void k_pl(
    const float* __restrict__ pair, const float* __restrict__ wln,
    const float* __restrict__ wpl, int blk, float* __restrict__ pl)
{
    const int gid = blockIdx.x*256 + threadIdx.x;
    const int s = gid >> 12;
    const int rem = gid & 4095;
    const int q = rem >> 7, kk = rem & 127;
    const float* pp = pair + (size_t)gid*CPC;
    float p[16];
    #pragma unroll
    for (int j = 0; j < 4; ++j) {
        const float4 v4 = *(const float4*)(pp + j*4);
        p[j*4]=v4.x; p[j*4+1]=v4.y; p[j*4+2]=v4.z; p[j*4+3]=v4.w;
    }
    float sm = 0.0f;
    #pragma unroll
    for (int j = 0; j < 16; ++j) sm += p[j];
    const float mu = sm * (1.0f/16.0f);
    float vq = 0.0f;
    #pragma unroll
    for (int j = 0; j < 16; ++j) { const float d = p[j]-mu; vq += d*d; }
    const float rs = rsqrtf(vq*(1.0f/16.0f) + 1e-5f);
    #pragma unroll
    for (int h = 0; h < 4; ++h) {
        float acc = 0.0f;
        #pragma unroll
        for (int j = 0; j < 16; ++j)
            acc += (p[j]-mu)*rs*wln[j] * wpl[j*12 + blk*4 + h];
        pl[(((size_t)s*HH + h)*QBQ + q)*KBK + kk] = acc;
    }
}

// ---------------------------------------------------------------------------
// K3: row LayerNorm (unweighted) of a [N,128] tensor
// ---------------------------------------------------------------------------
__global__ __launch_bounds__(128) void k_rowln(const float* __restrict__ x, float* __restrict__ y)
{
    const int n = blockIdx.x, c = threadIdx.x;
    __shared__ float red[128];
    const float v = x[(size_t)n*CAC + c];
    red[c] = v; __syncthreads();
    for (int off = 64; off > 0; off >>= 1) { if (c < off) red[c] += red[c+off]; __syncthreads(); }
    const float mu = red[0] * (1.0f/128.0f);
    __syncthreads();
    const float d = v - mu;
    red[c] = d*d; __syncthreads();
    for (int off = 64; off > 0; off >>= 1) { if (c < off) red[c] += red[c+off]; __syncthreads(); }
    const float var = red[0] * (1.0f/128.0f);
    y[(size_t)n*CAC + c] = d * rsqrtf(var + 1e-5f);
}

// ---------------------------------------------------------------------------
// K4: multi-job fp32 tiled GEMM. Each blockIdx.y is an independent job:
//     out[M,128-slice] = A[M,K] @ B1[K,128] (+ dual B2 / epilogues).
//     64-row tile, BK=32, 4x8 micro-tile, 256 threads, dynamic LDS.
// ---------------------------------------------------------------------------
struct GJob {
    const float *A, *A2, *asc, *B1, *B2, *bias, *extra;
    float* out;
    int K, bstride, ostride, epi;
};
struct GJobs { GJob j[4]; };

__global__ __launch_bounds__(256) void k_gemm_multi(GJobs jobs, int M)
{
    extern __shared__ float smem[];
    const GJob J = jobs.j[blockIdx.y];
    float* As  = smem;            // [32][68]
    float* Bs1 = smem + 2176;     // [32][128]
    float* Bs2 = smem + 2176 + 4096;

    const int tid = threadIdx.x;
    const int row0 = blockIdx.x * 64;
    const int m0 = (tid >> 4) * 4;
    const int c0 = (tid & 15) * 8;
    const bool dual = (J.B2 != nullptr);
    const int K = J.K;

    float acc1[4][8], acc2[4][8];
    #pragma unroll
    for (int i = 0; i < 4; ++i)
        #pragma unroll
        for (int j = 0; j < 8; ++j) { acc1[i][j] = 0.0f; acc2[i][j] = 0.0f; }

    for (int k0 = 0; k0 < K; k0 += 32) {
        #pragma unroll
        for (int j = 0; j < 2; ++j) {
            const int idx = tid + j*256;
            const int ar = idx >> 3;
            const int a4 = (idx & 7) * 4;
            const float4 av4 = *(const float4*)(J.A + (size_t)(row0+ar)*K + k0 + a4);
            float av[4] = {av4.x, av4.y, av4.z, av4.w};
            if (J.A2) {
                const float4 m4 = *(const float4*)(J.A2 + (size_t)(row0+ar)*K + k0 + a4);
                av[0]*=m4.x; av[1]*=m4.y; av[2]*=m4.z; av[3]*=m4.w;
            }
            if (J.asc) {
                const float4 s4 = *(const float4*)(J.asc + k0 + a4);
                av[0]*=s4.x; av[1]*=s4.y; av[2]*=s4.z; av[3]*=s4.w;
            }
            As[(a4+0)*68+ar]=av[0]; As[(a4+1)*68+ar]=av[1];
            As[(a4+2)*68+ar]=av[2]; As[(a4+3)*68+ar]=av[3];
        }
        #pragma unroll
        for (int j = 0; j < 4; ++j) {
            const int idx = tid + j*256;
            const int bk = idx >> 5;
            const int cc = (idx & 31) * 4;
            *(float4*)&Bs1[bk*128+cc] = *(const float4*)(J.B1 + (size_t)(k0+bk)*J.bstride + cc);
            if (dual)
                *(float4*)&Bs2[bk*128+cc] = *(const float4*)(J.B2 + (size_t)(k0+bk)*J.bstride + cc);
        }
        __syncthreads();
        if (dual) {
            #pragma unroll
            for (int k = 0; k < 32; ++k) {
                const float4 a4 = *(const float4*)&As[k*68+m0];
                const float4 b04 = *(const float4*)&Bs1[k*128+c0];
                const float4 b14 = *(const float4*)&Bs1[k*128+c0+4];
                const float4 d04 = *(const float4*)&Bs2[k*128+c0];
                const float4 d14 = *(const float4*)&Bs2[k*128+c0+4];
                const float a[4] = {a4.x, a4.y, a4.z, a4.w};
                const float b[8] = {b04.x,b04.y,b04.z,b04.w,b14.x,b14.y,b14.z,b14.w};
                const float bb[8] = {d04.x,d04.y,d04.z,d04.w,d14.x,d14.y,d14.z,d14.w};
                #pragma unroll
                for (int i = 0; i < 4; ++i)
                    #pragma unroll
                    for (int j = 0; j < 8; ++j) {
                        acc1[i][j] = fmaf(a[i], b[j],  acc1[i][j]);
                        acc2[i][j] = fmaf(a[i], bb[j], acc2[i][j]);
                    }
            }
        } else {
            #pragma unroll
            for (int k = 0; k < 32; ++k) {
                const float4 a4 = *(const float4*)&As[k*68+m0];
                const float4 b04 = *(const float4*)&Bs1[k*128+c0];
                const float4 b14 = *(const float4*)&Bs1[k*128+c0+4];
                const float a[4] = {a4.x, a4.y, a4.z, a4.w};
                const float b[8] = {b04.x,b04.y,b04.z,b04.w,b14.x,b14.y,b14.z,b14.w};
                #pragma unroll
                for (int i = 0; i < 4; ++i)
                    #pragma unroll
                    for (int j = 0; j < 8; ++j)
                        acc1[i][j] = fmaf(a[i], b[j], acc1[i][j]);
            }
        }
        __syncthreads();
    }

    #pragma unroll
    for (int i = 0; i < 4; ++i) {
        const int row = row0 + m0 + i;
        float vb[8];
        #pragma unroll
        for (int j = 0; j < 8; ++j) {
            const int col = c0 + j;
            float v = acc1[i][j];
            if (J.epi == EPI_PLAIN) {
                if (J.bias) v += J.bias[col];
            } else if (J.epi == EPI_SIG) {
                if (J.bias) v += J.bias[col];
                v = sig_(v);
            } else if (J.epi == EPI_RELU) {
                v = fmaxf(v, 0.0f);
            } else {
                v = sig_(v + J.bias[col]) * J.extra[(size_t)row*CAC + col] + acc2[i][j];
            }
            vb[j] = v;
        }
        float* op = J.out + (size_t)row*J.ostride + c0;
        *(float4*)(op  ) = make_float4(vb[0],vb[1],vb[2],vb[3]);
        *(float4*)(op+4) = make_float4(vb[4],vb[5],vb[6],vb[7]);
    }
}

// ---------------------------------------------------------------------------
// K5: flash-style attention, one subset per block, 512 threads:
//     tid = (kbhalf, h, q, dh). Online softmax, V-acc in registers,
//     K/V loads are wave-uniform broadcasts. LDS only for the 2-way
//     softmax-state merge (stride-17 padded).
// ---------------------------------------------------------------------------
__global__ __launch_bounds__(512) void k_attn2(
    const float* __restrict__ qh, const float* __restrict__ kh,
    const float* __restrict__ vh, const float* __restrict__ pls,
    float* __restrict__ oh)
{
    __shared__ float sm_m[256], sm_l[256], sm_acc[256*17];
    const int s = blockIdx.x, tid = threadIdx.x;
    const int kh2 = tid >> 8;
    const int h = (tid >> 6) & 3;
    const int q = (tid >> 1) & 31;
    const int dh = tid & 1;
    const int n0 = s*QBQ;
    const int kbase = n0 - 48 + kh2*64;
    const float SCALE = 0.17677669529663687f;

    float qr[32];
    {
        const float* qp = qh + (size_t)(n0+q)*CAC + h*DKD;
        #pragma unroll
        for (int j = 0; j < 8; ++j) {
            const float4 v4 = *(const float4*)(qp + j*4);
            qr[j*4]=v4.x*SCALE; qr[j*4+1]=v4.y*SCALE; qr[j*4+2]=v4.z*SCALE; qr[j*4+3]=v4.w*SCALE;
        }
    }
    const float* plp = pls + (((size_t)s*HH + h)*QBQ + q)*KBK + kh2*64;

    float m = -1e30f, l = 0.0f;
    float acc[16];
    #pragma unroll
    for (int j = 0; j < 16; ++j) acc[j] = 0.0f;

    for (int kb4 = 0; kb4 < 16; ++kb4) {
        const float4 p4 = *(const float4*)(plp + kb4*4);
        const float pv[4] = {p4.x, p4.y, p4.z, p4.w};
        #pragma unroll
        for (int j = 0; j < 4; ++j) {
            const int kb = kb4*4 + j;
            int kidx = kbase + kb; kidx = max(0, min(NN-1, kidx));
            const float* kp = kh + (size_t)kidx*CAC + h*DKD;
            float dot = 0.0f;
            #pragma unroll
            for (int jj = 0; jj < 8; ++jj) {
                const float4 kv = *(const float4*)(kp + jj*4);
                dot += qr[jj*4]*kv.x + qr[jj*4+1]*kv.y + qr[jj*4+2]*kv.z + qr[jj*4+3]*kv.w;
            }
            const float sv = dot + pv[j];
            if (sv > m) {
                const float corr = __expf(m - sv);
                l *= corr;
                #pragma unroll
                for (int d = 0; d < 16; ++d) acc[d] *= corr;
                m = sv;
            }
            const float w = __expf(sv - m);
            l += w;
            const float* vp = vh + (size_t)kidx*CAC + h*DKD + dh*16;
            #pragma unroll
            for (int jj = 0; jj < 4; ++jj) {
                const float4 vv = *(const float4*)(vp + jj*4);
                acc[jj*4]   = fmaf(w, vv.x, acc[jj*4]);
                acc[jj*4+1] = fmaf(w, vv.y, acc[jj*4+1]);
                acc[jj*4+2] = fmaf(w, vv.z, acc[jj*4+2]);
                acc[jj*4+3] = fmaf(w, vv.w, acc[jj*4+3]);
            }
        }
    }

    const int part = tid & 255;
    if (kh2 == 1) {
        sm_m[part] = m; sm_l[part] = l;
        #pragma unroll
        for (int j = 0; j < 16; ++j) sm_acc[part*17 + j] = acc[j];
    }
    __syncthreads();
    if (kh2 == 0) {
        const float m2 = sm_m[part], l2 = sm_l[part];
        const float mm = fmaxf(m, m2);
        const float c1 = __expf(m - mm), c2 = __expf(m2 - mm);
        const float inv = 1.0f / (l*c1 + l2*c2);
        float* op = oh + (size_t)(n0+q)*CAC + h*DKD + dh*16;
        #pragma unroll
        for (int jj = 0; jj < 4; ++jj) {
            float o0 = (acc[jj*4  ]*c1 + sm_acc[part*17+jj*4  ]*c2) * inv;
            float o1 = (acc[jj*4+1]*c1 + sm_acc[part*17+jj*4+1]*c2) * inv;
            float o2 = (acc[jj*4+2]*c1 + sm_acc[part*17+jj*4+2]*c2) * inv;
            float o3 = (acc[jj*4+3]*c1 + sm_acc[part*17+jj*4+3]*c2) * inv;
            *(float4*)op = make_float4(o0,o1,o2,o3);
            op += 4;
        }
    }
}

// ---------------------------------------------------------------------------
// K5-fallback: original LDS-logits attention (used only if ws too small)
// ---------------------------------------------------------------------------
__global__ __launch_bounds__(256) void k_attn(
    const float* __restrict__ qh, const float* __restrict__ kh,
    const float* __restrict__ vh, const float* __restrict__ pair,
    const float* __restrict__ wln, const float* __restrict__ wpl,
    int blk, float* __restrict__ oh)
{
    __shared__ float L[4*32*128];
    const int s = blockIdx.x, tid = threadIdx.x;
    const int n0 = s*QBQ;
    const int kbase = n0 - 48;
    const float SCALE = 0.17677669529663687f;

    for (int idx = tid; idx < QBQ*KBK; idx += 256) {
        const int q = idx >> 7, kk = idx & 127;
        const float* pp = pair + ((size_t)(n0+q)*KBK + kk)*CPC;
        float p[16];
        #pragma unroll
        for (int j = 0; j < 4; ++j) {
            const float4 v4 = *(const float4*)(pp + j*4);
            p[j*4]=v4.x; p[j*4+1]=v4.y; p[j*4+2]=v4.z; p[j*4+3]=v4.w;
        }
        float sm = 0.0f;
        #pragma unroll
        for (int j = 0; j < 16; ++j) sm += p[j];
        const float mu = sm * (1.0f/16.0f);
        float sq = 0.0f;
        #pragma unroll
        for (int j = 0; j < 16; ++j) { const float d = p[j]-mu; sq += d*d; }
        const float rs = rsqrtf(sq*(1.0f/16.0f) + 1e-5f);
        float lg[4] = {0,0,0,0};
        #pragma unroll
        for (int j = 0; j < 16; ++j) {
            const float xn = (p[j]-mu)*rs*wln[j];
            const float* wr = wpl + j*12 + blk*4;
            lg[0] += xn*wr[0]; lg[1] += xn*wr[1]; lg[2] += xn*wr[2]; lg[3] += xn*wr[3];
        }
        #pragma unroll
        for (int h = 0; h < 4; ++h) L[(h*32+q)*128 + kk] = lg[h];
    }
    __syncthreads();
    {
        const int hq = tid >> 1, half = tid & 1;
        const int h = hq >> 5, q = hq & 31;
        float qr[32];
        const float* qp = qh + (size_t)(n0+q)*CAC + h*DKD;
        #pragma unroll
        for (int j = 0; j < 8; ++j) {
            const float4 v4 = *(const float4*)(qp + j*4);
            qr[j*4]=v4.x*SCALE; qr[j*4+1]=v4.y*SCALE; qr[j*4+2]=v4.z*SCALE; qr[j*4+3]=v4.w*SCALE;
        }
        const int kb0 = half*64;
        for (int kbl = 0; kbl < 64; ++kbl) {
            const int kb = kb0 + ((kbl + hq) & 63);
            int kidx = kbase + kb; kidx = max(0, min(NN-1, kidx));
            const float* kp = kh + (size_t)kidx*CAC + h*DKD;
            float acc = 0.0f;
            #pragma unroll
            for (int j = 0; j < 8; ++j) {
                const float4 kv = *(const float4*)(kp + j*4);
                acc += qr[j*4]*kv.x + qr[j*4+1]*kv.y + qr[j*4+2]*kv.z + qr[j*4+3]*kv.w;
            }
            L[(h*32+q)*128 + kb] += acc;
        }
    }
    __syncthreads();
    if (tid < 128) {
        float* row = &L[tid*128];
        float mx = -3.0e38f;
        for (int kbl = 0; kbl < 128; ++kbl) { const int kb = (kbl + tid) & 127; mx = fmaxf(mx, row[kb]); }
        float sum = 0.0f;
        for (int kbl = 0; kbl < 128; ++kbl) {
            const int kb = (kbl + tid) & 127;
            const float e = __expf(row[kb]-mx); row[kb] = e; sum += e;
        }
        const float inv = 1.0f / sum;
        for (int kbl = 0; kbl < 128; ++kbl) { const int kb = (kbl + tid) & 127; row[kb] *= inv; }
    }
    __syncthreads();
    {
        const int q = tid >> 3, h = (tid >> 1) & 3, dh = tid & 1;
        float o[16];
        #pragma unroll
        for (int j = 0; j < 16; ++j) o[j] = 0.0f;
        const float* lrow = &L[(h*32+q)*128];
        for (int kbl = 0; kbl < 128; ++kbl) {
            const int kb = (kbl + tid) & 127;
            const float aw = lrow[kb];
            int kidx = kbase + kb; kidx = max(0, min(NN-1, kidx));
            const float* vp = vh + (size_t)kidx*CAC + h*DKD + dh*16;
            #pragma unroll
            for (int j = 0; j < 4; ++j) {
                const float4 vv = *(const float4*)(vp + j*4);
                o[j*4]   = fmaf(aw, vv.x, o[j*4]);
                o[j*4+1] = fmaf(aw, vv.y, o[j*4+1]);
                o[j*4+2] = fmaf(aw, vv.z, o[j*4+2]);
                o[j*4+3] = fmaf(aw, vv.w, o[j*4+3]);
            }
        }
        float* op = oh + (size_t)(n0+q)*CAC + h*DKD + dh*16;
        #pragma unroll
        for (int j = 0; j < 4; ++j)
            *(float4*)(op + j*4) = make_float4(o[j*4], o[j*4+1], o[j*4+2], o[j*4+3]);
    }
}

// ---------------------------------------------------------------------------
// small elementwise kernels
// ---------------------------------------------------------------------------
__global__ __launch_bounds__(256) void k_axpy_mul(float4* __restrict__ y,
    const float4* __restrict__ a, const float4* __restrict__ b)
{
    const int i = blockIdx.x*256 + threadIdx.x;
    float4 yv = y[i]; const float4 av = a[i], bv = b[i];
    yv.x += av.x*bv.x; yv.y += av.y*bv.y; yv.z += av.z*bv.z; yv.w += av.w*bv.w;
    y[i] = yv;
}

__global__ __launch_bounds__(256) void k_silu_mul(float4* __restrict__ h1,
    const float4* __restrict__ h2)
{
    const int i = blockIdx.x*256 + threadIdx.x;
    float4 a = h1[i]; const float4 b = h2[i];
    a.x = a.x * sig_(a.x) * b.x;
    a.y = a.y * sig_(a.y) * b.y;
    a.z = a.z * sig_(a.z) * b.z;
    a.w = a.w * sig_(a.w) * b.w;
    h1[i] = a;
}

__global__ __launch_bounds__(256) void k_token_reduce(
    const float* __restrict__ tok, const float* __restrict__ msk, float* __restrict__ out)
{
    const int gid = blockIdx.x*256 + threadIdx.x;
    const int t = gid / CTC, c = gid - t*CTC;
    float num = 0.0f, den = 0.0f;
    #pragma unroll
    for (int a = 0; a < AA; ++a) {
        const float mv = msk[t*AA + a];
        num += tok[(size_t)(t*AA+a)*CTC + c] * mv;
        den += mv;
    }
    out[gid] = num / fmaxf(den, 1e-10f);
}

// ---------------------------------------------------------------------------
// launch
// ---------------------------------------------------------------------------
static inline GJob mkjob(const float* A, const float* A2, const float* asc,
                         const float* B1, const float* B2, const float* bias,
                         const float* extra, float* out, int K, int bstride,
                         int ostride, int epi)
{
    GJob j; j.A=A; j.A2=A2; j.asc=asc; j.B1=B1; j.B2=B2; j.bias=bias;
    j.extra=extra; j.out=out; j.K=K; j.bstride=bstride; j.ostride=ostride; j.epi=epi;
    return j;
}

extern "C" void kernel_launch(void* const* d_in, const int* in_sizes, int n_in,
                              void* d_out, int out_size, void* d_ws, size_t ws_size,
                              hipStream_t stream)
{
    const float* positions = (const float*)d_in[0];
    const float* maskp     = (const float*)d_in[1];
    const int*   element   = (const int*  )d_in[2];
    const float* charge    = (const float*)d_in[3];
    const int*   chars     = (const int*  )d_in[4];
    const int*   uid       = (const int*  )d_in[5];
    const float* w_ref_pos      = (const float*)d_in[6];
    const float* w_ref_mask     = (const float*)d_in[7];
    const float* w_ref_element  = (const float*)d_in[8];
    const float* w_ref_charge   = (const float*)d_in[9];
    const float* w_ref_atom_name= (const float*)d_in[10];
    const float* w_s2p_row      = (const float*)d_in[11];
    const float* w_s2p_col      = (const float*)d_in[12];
    const float* w_pair_offsets = (const float*)d_in[13];
    const float* w_pair_dist    = (const float*)d_in[14];
    const float* w_pair_mask    = (const float*)d_in[15];
    const float* w_pair_mlp1    = (const float*)d_in[16];
    const float* w_pair_mlp2    = (const float*)d_in[17];
    const float* w_pair_mlp3    = (const float*)d_in[18];
    const float* w_pair_ln      = (const float*)d_in[19];
    const float* w_pair_logits  = (const float*)d_in[20];
    const float* aq_lnw = (const float*)d_in[21];
    const float* aq_gw  = (const float*)d_in[22];
    const float* aq_gb  = (const float*)d_in[23];
    const float* aq_sw  = (const float*)d_in[24];
    const float* ak_lnw = (const float*)d_in[25];
    const float* ak_gw  = (const float*)d_in[26];
    const float* ak_gb  = (const float*)d_in[27];
    const float* ak_sw  = (const float*)d_in[28];
    const float* wq     = (const float*)d_in[29];
    const float* bq     = (const float*)d_in[30];
    const float* wk     = (const float*)d_in[31];
    const float* wv     = (const float*)d_in[32];
    const float* wg     = (const float*)d_in[33];
    const float* azi_w  = (const float*)d_in[34];
    const float* azi_cw = (const float*)d_in[35];
    const float* azi_cb = (const float*)d_in[36];
    const float* t_lnw  = (const float*)d_in[37];
    const float* t_gw   = (const float*)d_in[38];
    const float* t_gb   = (const float*)d_in[39];
    const float* t_sw   = (const float*)d_in[40];
    const float* glu1   = (const float*)d_in[41];
    const float* glu2   = (const float*)d_in[42];
    const float* t_azi_w  = (const float*)d_in[43];
    const float* t_azi_cw = (const float*)d_in[44];
    const float* t_azi_cb = (const float*)d_in[45];
    const float* w_project= (const float*)d_in[46];

    float* token_o = (float*)d_out;
    float* qact = token_o + 1572864;
    float* qsc  = token_o + 3670016;
    float* pair = token_o + 5767168;

    float* ws = (float*)d_ws;
    const size_t M2 = 2097152;
    float* w_qn = ws;
    float* w_qa = ws + M2;
    float* w_rq = ws + 2*M2;
    float* w_rk = ws + 2*M2 + 262144;
    float* w_xq = ws + 2*M2 + 524288;
    float* w_xk = w_xq + M2;
    float* w_q  = w_xk + M2;
    float* w_k  = w_q  + M2;
    float* w_v  = w_k  + M2;
    float* w_g  = w_v  + M2;
    float* w_o  = w_g  + M2;
    const size_t BASE = 19398656ull;          // floats used by the core buffers
    const size_t PL_SLICE = 8388608ull;       // S*H*QB*KB floats per block
    float* w_h1 = w_q;
    float* w_h2 = w_v;
    float* w_tok= w_q;
    float* pl   = ws + BASE;

    const size_t ws_floats = ws_size / 4;
    // mode 2: pl for all 3 blocks; mode 1: one pl slot, recompute per block;
    // mode 0: no room -> original in-attention pl (slow path).
    const int mode = (ws_floats >= BASE + 3*PL_SLICE) ? 2
                   : (ws_floats >= BASE + PL_SLICE)   ? 1 : 0;
    const int npl = (mode == 2) ? 3 : (mode == 1) ? 1 : 0;

    (void)in_sizes; (void)n_in; (void)out_size;

    const dim3 blk128(128), blk256(256), blk512(512);
    const size_t SH1 = (2176 + 4096) * 4;          // non-dual LDS bytes
    const size_t SH2 = (2176 + 8192) * 4;          // dual LDS bytes

    k_atom_cond<<<NN, blk128, 0, stream>>>(positions, maskp, element, charge, chars,
        w_ref_pos, w_ref_mask, w_ref_element, w_ref_charge, w_ref_atom_name,
        w_s2p_row, w_s2p_col, qsc, qact, w_qn, w_rq, w_rk);

    k_pair<<<(SS*QBQ*KBK)/256, blk256, 0, stream>>>(positions, uid, w_rq, w_rk,
        w_pair_offsets, w_pair_dist, w_pair_mask, w_pair_mlp1, w_pair_mlp2, w_pair_mlp3,
        w_pair_ln, w_pair_logits, pair, pl, npl);

    for (int i = 0; i < 3; ++i) {
        const size_t oM = (size_t)i*CAC*CAC;
        const size_t oV = (size_t)i*CAC;
        const size_t oG = (size_t)i*CAC*2*CAC;

        k_rowln<<<NN, blk128, 0, stream>>>(qact, w_qa);
        {   // adaLN for q-side and k-side (dual-B jobs)
            GJobs js{};
            js.j[0] = mkjob(w_qn, nullptr, aq_lnw+oV, aq_gw+oM, aq_sw+oM, aq_gb+oV, w_qa, w_xq, CAC, CAC, CAC, EPI_ADA);
            js.j[1] = mkjob(w_qn, nullptr, ak_lnw+oV, ak_gw+oM, ak_sw+oM, ak_gb+oV, w_qa, w_xk, CAC, CAC, CAC, EPI_ADA);
            k_gemm_multi<<<dim3(NN/64,2), blk256, SH2, stream>>>(js, NN);
        }
        {   // q, k, v, g projections in one launch
            GJobs js{};
            js.j[0] = mkjob(w_xq, nullptr, nullptr, wq+oM, nullptr, bq+oV, nullptr, w_q, CAC, CAC, CAC, EPI_PLAIN);
            js.j[1] = mkjob(w_xk, nullptr, nullptr, wk+oM, nullptr, nullptr, nullptr, w_k, CAC, CAC, CAC, EPI_PLAIN);
            js.j[2] = mkjob(w_xk, nullptr, nullptr, wv+oM, nullptr, nullptr, nullptr, w_v, CAC, CAC, CAC, EPI_PLAIN);
            js.j[3] = mkjob(w_xq, nullptr, nullptr, wg+oM, nullptr, nullptr, nullptr, w_g, CAC, CAC, CAC, EPI_SIG);
            k_gemm_multi<<<dim3(NN/64,4), blk256, SH1, stream>>>(js, NN);
        }
        if (mode == 2) {
            k_attn2<<<SS, blk512, 0, stream>>>(w_q, w_k, w_v, pl + (size_t)i*PL_SLICE, w_o);
        } else if (mode == 1) {
            if (i > 0)
                k_pl<<<(SS*QBQ*KBK)/256, blk256, 0, stream>>>(pair, w_pair_ln, w_pair_logits, i, pl);
            k_attn2<<<SS, blk512, 0, stream>>>(w_q, w_k, w_v, pl, w_o);
        } else {
            k_attn<<<SS, blk256, 0, stream>>>(w_q, w_k, w_v, pair, w_pair_ln, w_pair_logits, i, w_o);
        }
        {   // o-projection (gated by g) and adaptive-zero-init cond gate
            GJobs js{};
            js.j[0] = mkjob(w_o, w_g, nullptr, azi_w+oM, nullptr, nullptr, nullptr, w_xq, CAC, CAC, CAC, EPI_PLAIN);
            js.j[1] = mkjob(qsc, nullptr, nullptr, azi_cw+oM, nullptr, azi_cb+oV, nullptr, w_xk, CAC, CAC, CAC, EPI_SIG);
            k_gemm_multi<<<dim3(NN/64,2), blk256, SH1, stream>>>(js, NN);
        }
        k_axpy_mul<<<2048, blk256, 0, stream>>>((float4*)qact, (const float4*)w_xq, (const float4*)w_xk);
        k_rowln<<<NN, blk128, 0, stream>>>(qact, w_qa);
        {   // transition adaLN
            GJobs js{};
            js.j[0] = mkjob(w_qn, nullptr, t_lnw+oV, t_gw+oM, t_sw+oM, t_gb+oV, w_qa, w_xq, CAC, CAC, CAC, EPI_ADA);
            k_gemm_multi<<<dim3(NN/64,1), blk256, SH2, stream>>>(js, NN);
        }
        {   // glu1 / glu2, each as two 128-col jobs
            GJobs js{};
            js.j[0] = mkjob(w_xq, nullptr, nullptr, glu1+oG,     nullptr, nullptr, nullptr, w_h1,     CAC, 2*CAC, 2*CAC, EPI_PLAIN);
            js.j[1] = mkjob(w_xq, nullptr, nullptr, glu1+oG+128, nullptr, nullptr, nullptr, w_h1+128, CAC, 2*CAC, 2*CAC, EPI_PLAIN);
            js.j[2] = mkjob(w_xq, nullptr, nullptr, glu2+oG,     nullptr, nullptr, nullptr, w_h2,     CAC, 2*CAC, 2*CAC, EPI_PLAIN);
            js.j[3] = mkjob(w_xq, nullptr, nullptr, glu2+oG+128, nullptr, nullptr, nullptr, w_h2+128, CAC, 2*CAC, 2*CAC, EPI_PLAIN);
            k_gemm_multi<<<dim3(NN/64,4), blk256, SH1, stream>>>(js, NN);
        }
        k_silu_mul<<<4096, blk256, 0, stream>>>((float4*)w_h1, (const float4*)w_h2);
        {   // transition output proj (K=256) + cond gate
            GJobs js{};
            js.j[0] = mkjob(w_h1, nullptr, nullptr, t_azi_w+oG, nullptr, nullptr, nullptr, w_o, 2*CAC, CAC, CAC, EPI_PLAIN);
            js.j[1] = mkjob(qsc, nullptr, nullptr, t_azi_cw+oM, nullptr, t_azi_cb+oV, nullptr, w_xk, CAC, CAC, CAC, EPI_SIG);
            k_gemm_multi<<<dim3(NN/64,2), blk256, SH1, stream>>>(js, NN);
        }
        k_axpy_mul<<<2048, blk256, 0, stream>>>((float4*)qact, (const float4*)w_o, (const float4*)w_xk);
    }

    {   // token projection as three 128-col jobs
        GJobs js{};
        js.j[0] = mkjob(qact, nullptr, nullptr, w_project,     nullptr, nullptr, nullptr, w_tok,     CAC, CTC, CTC, EPI_RELU);
        js.j[1] = mkjob(qact, nullptr, nullptr, w_project+128, nullptr, nullptr, nullptr, w_tok+128, CAC, CTC, CTC, EPI_RELU);
        js.j[2] = mkjob(qact, nullptr, nullptr, w_project+256, nullptr, nullptr, nullptr, w_tok+256, CAC, CTC, CTC, EPI_RELU);
        k_gemm_multi<<<dim3(NN/64,3), blk256, SH1, stream>>>(js, NN);
    }
    k_token_reduce<<<(TT*CTC)/256, blk256, 0, stream>>>(w_tok, maskp, token_o);
}

// Round 5
// 1032.914 us; speedup vs baseline: 2.0226x; 2.0226x over previous
//
#include <hip/hip_runtime.h>
#include <math.h>

#define TT 4096
#define AA 4
#define NN 16384
#define QBQ 32
#define KBK 128
#define SS 512
#define HH 4
#define DKD 32
#define CAC 128
#define CPC 16
#define CTC 384

#define EPI_PLAIN 0
#define EPI_SIG   1
#define EPI_RELU  3

typedef __attribute__((ext_vector_type(8))) short bf16x8;
typedef __attribute__((ext_vector_type(4))) short s16x4;
typedef __attribute__((ext_vector_type(4))) float f32x4;

__device__ __forceinline__ float sig_(float x) { return 1.0f / (1.0f + __expf(-x)); }
__device__ __forceinline__ short f2bf(float f) {
    unsigned u = __float_as_uint(f);
    unsigned r = (u + 0x7FFFu + ((u >> 16) & 1u)) >> 16;
    return (short)r;
}
__device__ __forceinline__ float b2f(short s) {
    return __uint_as_float(((unsigned)(unsigned short)s) << 16);
}

// ---------------------------------------------------------------------------
// K0: weight prep — fp32 [K][NC] -> bf16 transposed [NC][K], optional
//     per-row (k) scale (folds LN weight into the matrix).
// ---------------------------------------------------------------------------
struct PEnt { const float* src; const float* rs; short* dst; int K; int NC; };
struct PTab { PEnt e[49]; };

__global__ __launch_bounds__(256) void k_prep(PTab tab)
{
    const PEnt e = tab.e[blockIdx.y];
    const int ntx = e.NC >> 5, nty = e.K >> 5, nt = ntx * nty;
    __shared__ float sm[32][33];
    const int lx = threadIdx.x & 31, ly = threadIdx.x >> 5;
    for (int t = blockIdx.x; t < nt; t += gridDim.x) {
        const int ty = t / ntx, tx = t - ty * ntx;
        #pragma unroll
        for (int j = 0; j < 4; ++j) {
            const int k = ty * 32 + ly + j * 8;
            const int n = tx * 32 + lx;
            float v = e.src[(size_t)k * e.NC + n];
            if (e.rs) v *= e.rs[k];
            sm[ly + j * 8][lx] = v;
        }
        __syncthreads();
        #pragma unroll
        for (int j = 0; j < 4; ++j) {
            const int n = tx * 32 + ly + j * 8;
            const int k = ty * 32 + lx;
            e.dst[(size_t)n * e.K + k] = f2bf(sm[lx][ly + j * 8]);
        }
        __syncthreads();
    }
}

// ---------------------------------------------------------------------------
// K1: per-atom conditioning
// ---------------------------------------------------------------------------
__global__ __launch_bounds__(128) void k_atom_cond(
    const float* __restrict__ pos, const float* __restrict__ msk,
    const int* __restrict__ elem, const float* __restrict__ chg,
    const int* __restrict__ chars,
    const float* __restrict__ w_pos, const float* __restrict__ w_msk,
    const float* __restrict__ w_elem, const float* __restrict__ w_chg,
    const float* __restrict__ w_name,
    const float* __restrict__ w_row, const float* __restrict__ w_col,
    float* __restrict__ qsc, float* __restrict__ qact,
    short* __restrict__ qsc_bf, short* __restrict__ qn_bf,
    float* __restrict__ rq, float* __restrict__ rk)
{
    const int n = blockIdx.x, c = threadIdx.x;
    const float p0 = pos[n*3+0], p1 = pos[n*3+1], p2 = pos[n*3+2];
    const float m = msk[n];
    const int   el = elem[n];
    const float ach = asinhf(chg[n]);
    const int c0 = chars[n*4+0], c1 = chars[n*4+1], c2 = chars[n*4+2], c3 = chars[n*4+3];

    float a = p0*w_pos[c] + p1*w_pos[CAC+c] + p2*w_pos[2*CAC+c]
            + m*w_msk[c] + w_elem[el*CAC+c] + ach*w_chg[c]
            + w_name[(c0      )*CAC+c] + w_name[( 64+c1)*CAC+c]
            + w_name[(128+c2)*CAC+c] + w_name[(192+c3)*CAC+c];
    a *= m;

    const size_t base = (size_t)n*CAC + c;
    qsc[base] = a; qact[base] = a; qsc_bf[base] = f2bf(a);

    __shared__ float red[128];
    __shared__ float sh[128];
    red[c] = a; __syncthreads();
    for (int off = 64; off > 0; off >>= 1) { if (c < off) red[c] += red[c+off]; __syncthreads(); }
    const float mu = red[0] * (1.0f/128.0f);
    __syncthreads();
    const float d = a - mu;
    red[c] = d*d; __syncthreads();
    for (int off = 64; off > 0; off >>= 1) { if (c < off) red[c] += red[c+off]; __syncthreads(); }
    const float var = red[0] * (1.0f/128.0f);
    qn_bf[base] = f2bf(d * rsqrtf(var + 1e-5f));
    __syncthreads();
    sh[c] = fmaxf(a, 0.0f);
    __syncthreads();
    if (c < 32) {
        const float* w = (c < 16) ? w_row : w_col;
        const int cc = c & 15;
        float acc = 0.0f;
        #pragma unroll 8
        for (int r = 0; r < 128; ++r) acc += sh[r] * w[r*CPC + cc];
        if (c < 16) rq[(size_t)n*CPC + cc] = acc;
        else        rk[(size_t)n*CPC + cc] = acc;
    }
}

// ---------------------------------------------------------------------------
// K2: pair conditioning + MLP residual; also emits pl (bf16) for all 3 blocks
// ---------------------------------------------------------------------------
__global__ __launch_bounds__(256) void k_pair(
    const float* __restrict__ pos, const int* __restrict__ uid,
    const float* __restrict__ rq, const float* __restrict__ rk,
    const float* __restrict__ w_ofs, const float* __restrict__ w_dist,
    const float* __restrict__ w_pm,
    const float* __restrict__ mlp1, const float* __restrict__ mlp2,
    const float* __restrict__ mlp3,
    const float* __restrict__ wln, const float* __restrict__ wpl,
    float* __restrict__ pair, short* __restrict__ plb)
{
    __shared__ float sm1[256], sm2[256], sm3[256], sofs[48], sdist[16], smask[16];
    __shared__ float swln[16], swpl[192];
    const int tid = threadIdx.x;
    sm1[tid] = mlp1[tid]; sm2[tid] = mlp2[tid]; sm3[tid] = mlp3[tid];
    if (tid < 48) sofs[tid] = w_ofs[tid];
    if (tid < 16) { sdist[tid] = w_dist[tid]; smask[tid] = w_pm[tid]; swln[tid] = wln[tid]; }
    if (tid < 192) swpl[tid] = wpl[tid];
    __syncthreads();

    const int gid = blockIdx.x*256 + tid;
    const int s = gid >> 12;
    const int rem = gid & 4095;
    const int q = rem >> 7, kk = rem & 127;
    const int n = s*QBQ + q;
    int kidx = s*QBQ - 48 + kk; kidx = max(0, min(NN-1, kidx));

    const float v = (uid[n] == uid[kidx]) ? 1.0f : 0.0f;
    const float o0 = pos[n*3+0]-pos[kidx*3+0];
    const float o1 = pos[n*3+1]-pos[kidx*3+1];
    const float o2 = pos[n*3+2]-pos[kidx*3+2];
    const float sq = o0*o0 + o1*o1 + o2*o2;
    const float inv = 1.0f/(1.0f + sq);

    const float* rqp = rq + (size_t)n*CPC;
    const float* rkp = rk + (size_t)kidx*CPC;

    float p[16], t1[16], t2[16];
    #pragma unroll
    for (int j = 0; j < 16; ++j)
        p[j] = v*(o0*sofs[j] + o1*sofs[16+j] + o2*sofs[32+j] + inv*sdist[j] + smask[j])
             + rqp[j] + rkp[j];
    #pragma unroll
    for (int j = 0; j < 16; ++j) {
        float acc = 0.0f;
        #pragma unroll
        for (int r = 0; r < 16; ++r) acc += fmaxf(p[r], 0.0f) * sm1[r*16+j];
        t1[j] = acc;
    }
    #pragma unroll
    for (int j = 0; j < 16; ++j) {
        float acc = 0.0f;
        #pragma unroll
        for (int r = 0; r < 16; ++r) acc += fmaxf(t1[r], 0.0f) * sm2[r*16+j];
        t2[j] = acc;
    }
    #pragma unroll
    for (int j = 0; j < 16; ++j) {
        float acc = 0.0f;
        #pragma unroll
        for (int r = 0; r < 16; ++r) acc += fmaxf(t2[r], 0.0f) * sm3[r*16+j];
        t1[j] = p[j] + acc;
    }
    float* op = pair + (size_t)gid*CPC;
    #pragma unroll
    for (int j = 0; j < 4; ++j)
        *(float4*)(op + j*4) = make_float4(t1[j*4], t1[j*4+1], t1[j*4+2], t1[j*4+3]);

    // LN over 16 channels + projection to 12 logit planes (3 blocks x 4 heads)
    float sm = 0.0f;
    #pragma unroll
    for (int j = 0; j < 16; ++j) sm += t1[j];
    const float mu = sm * (1.0f/16.0f);
    float vq = 0.0f;
    #pragma unroll
    for (int j = 0; j < 16; ++j) { const float dd = t1[j]-mu; vq += dd*dd; }
    const float rs = rsqrtf(vq*(1.0f/16.0f) + 1e-5f);
    float xn[16];
    #pragma unroll
    for (int j = 0; j < 16; ++j) xn[j] = (t1[j]-mu)*rs*swln[j];
    #pragma unroll
    for (int i = 0; i < 3; ++i) {
        #pragma unroll
        for (int h = 0; h < 4; ++h) {
            float acc = 0.0f;
            #pragma unroll
            for (int j = 0; j < 16; ++j) acc += xn[j] * swpl[j*12 + i*4 + h];
            plb[((((size_t)i*SS + s)*HH + h)*QBQ + q)*KBK + kk] = f2bf(acc);
        }
    }
}

// ---------------------------------------------------------------------------
// K3: row LayerNorm (unweighted) -> fp32
// ---------------------------------------------------------------------------
__global__ __launch_bounds__(128) void k_rowln(const float* __restrict__ x, float* __restrict__ y)
{
    const int n = blockIdx.x, c = threadIdx.x;
    __shared__ float red[128];
    const float v = x[(size_t)n*CAC + c];
    red[c] = v; __syncthreads();
    for (int off = 64; off > 0; off >>= 1) { if (c < off) red[c] += red[c+off]; __syncthreads(); }
    const float mu = red[0] * (1.0f/128.0f);
    __syncthreads();
    const float d = v - mu;
    red[c] = d*d; __syncthreads();
    for (int off = 64; off > 0; off >>= 1) { if (c < off) red[c] += red[c+off]; __syncthreads(); }
    const float var = red[0] * (1.0f/128.0f);
    y[(size_t)n*CAC + c] = d * rsqrtf(var + 1e-5f);
}

// ---------------------------------------------------------------------------
// K4: bf16 MFMA multi-job GEMM.  out[16384,128] = A[16384,K]@B[K,128]
//     A: bf16 row-major [M][K].  Bt: bf16 transposed [128][K].
//     Tile 128x128, K_STEP=64, XOR-swizzled LDS, 4 waves x (2x8) 16x16x32.
// ---------------------------------------------------------------------------
struct MJob {
    const short* A; const short* Bt; const float* bias;
    float* outF; short* outB;
    int K; int ostride; int epi;
};
struct MJobs { MJob j[8]; };

__global__ __launch_bounds__(256) void k_mm(MJobs jobs)
{
    __shared__ short As[128*64];
    __shared__ short Bs[128*64];
    const MJob J = jobs.j[blockIdx.y];
    const int tid = threadIdx.x;
    const int wave = tid >> 6, lane = tid & 63;
    const int l15 = lane & 15, l4 = lane >> 4;
    const int row0 = blockIdx.x * 128;
    const int K = J.K;

    f32x4 acc[2][8];
    #pragma unroll
    for (int m = 0; m < 2; ++m)
        #pragma unroll
        for (int n = 0; n < 8; ++n) acc[m][n] = (f32x4){0.f,0.f,0.f,0.f};

    for (int k0 = 0; k0 < K; k0 += 64) {
        #pragma unroll
        for (int j = 0; j < 4; ++j) {
            const int u = tid + j*256;
            const int r = u >> 3, ug = u & 7;
            const bf16x8 av = *(const bf16x8*)(J.A + (size_t)(row0 + r)*K + k0 + ug*8);
            *(bf16x8*)&As[r*64 + ((ug ^ (r & 7)) * 8)] = av;
            const bf16x8 bv = *(const bf16x8*)(J.Bt + (size_t)r*K + k0 + ug*8);
            *(bf16x8*)&Bs[r*64 + ((ug ^ (r & 7)) * 8)] = bv;
        }
        __syncthreads();
        #pragma unroll
        for (int ks = 0; ks < 2; ++ks) {
            bf16x8 af[2], bfr[8];
            #pragma unroll
            for (int m = 0; m < 2; ++m) {
                const int r = wave*32 + m*16 + l15;
                af[m] = *(const bf16x8*)&As[r*64 + (((ks*4 + l4) ^ (r & 7)) * 8)];
            }
            #pragma unroll
            for (int n = 0; n < 8; ++n) {
                const int c = n*16 + l15;
                bfr[n] = *(const bf16x8*)&Bs[c*64 + (((ks*4 + l4) ^ (c & 7)) * 8)];
            }
            #pragma unroll
            for (int m = 0; m < 2; ++m)
                #pragma unroll
                for (int n = 0; n < 8; ++n)
                    acc[m][n] = __builtin_amdgcn_mfma_f32_16x16x32_bf16(af[m], bfr[n], acc[m][n], 0, 0, 0);
        }
        __syncthreads();
    }

    float bval[8];
    #pragma unroll
    for (int n = 0; n < 8; ++n) bval[n] = 0.0f;
    if (J.bias) {
        #pragma unroll
        for (int n = 0; n < 8; ++n) bval[n] = J.bias[n*16 + l15];
    }
    const int epi = J.epi;
    #pragma unroll
    for (int m = 0; m < 2; ++m) {
        #pragma unroll
        for (int n = 0; n < 8; ++n) {
            const int col = n*16 + l15;
            #pragma unroll
            for (int reg = 0; reg < 4; ++reg) {
                const int row = row0 + wave*32 + m*16 + l4*4 + reg;
                float v = acc[m][n][reg] + bval[n];
                if (epi == EPI_SIG)  v = sig_(v);
                if (epi == EPI_RELU) v = fmaxf(v, 0.0f);
                if (J.outB) J.outB[(size_t)row*J.ostride + col] = f2bf(v);
                else        J.outF[(size_t)row*J.ostride + col] = v;
            }
        }
    }
}

// ---------------------------------------------------------------------------
// K5: flash attention (pl in bf16)
// ---------------------------------------------------------------------------
__global__ __launch_bounds__(512) void k_attn2(
    const float* __restrict__ qh, const float* __restrict__ kh,
    const float* __restrict__ vh, const short* __restrict__ pls,
    float* __restrict__ oh)
{
    __shared__ float sm_m[256], sm_l[256], sm_acc[256*17];
    const int s = blockIdx.x, tid = threadIdx.x;
    const int kh2 = tid >> 8;
    const int h = (tid >> 6) & 3;
    const int q = (tid >> 1) & 31;
    const int dh = tid & 1;
    const int n0 = s*QBQ;
    const int kbase = n0 - 48 + kh2*64;
    const float SCALE = 0.17677669529663687f;

    float qr[32];
    {
        const float* qp = qh + (size_t)(n0+q)*CAC + h*DKD;
        #pragma unroll
        for (int j = 0; j < 8; ++j) {
            const float4 v4 = *(const float4*)(qp + j*4);
            qr[j*4]=v4.x*SCALE; qr[j*4+1]=v4.y*SCALE; qr[j*4+2]=v4.z*SCALE; qr[j*4+3]=v4.w*SCALE;
        }
    }
    const short* plp = pls + (((size_t)s*HH + h)*QBQ + q)*KBK + kh2*64;

    float m = -1e30f, l = 0.0f;
    float acc[16];
    #pragma unroll
    for (int j = 0; j < 16; ++j) acc[j] = 0.0f;

    for (int kb4 = 0; kb4 < 16; ++kb4) {
        const s16x4 p4 = *(const s16x4*)(plp + kb4*4);
        float pv[4];
        #pragma unroll
        for (int j = 0; j < 4; ++j) pv[j] = b2f(p4[j]);
        #pragma unroll
        for (int j = 0; j < 4; ++j) {
            const int kb = kb4*4 + j;
            int kidx = kbase + kb; kidx = max(0, min(NN-1, kidx));
            const float* kp = kh + (size_t)kidx*CAC + h*DKD;
            float dot = 0.0f;
            #pragma unroll
            for (int jj = 0; jj < 8; ++jj) {
                const float4 kv = *(const float4*)(kp + jj*4);
                dot += qr[jj*4]*kv.x + qr[jj*4+1]*kv.y + qr[jj*4+2]*kv.z + qr[jj*4+3]*kv.w;
            }
            const float sv = dot + pv[j];
            if (sv > m) {
                const float corr = __expf(m - sv);
                l *= corr;
                #pragma unroll
                for (int d = 0; d < 16; ++d) acc[d] *= corr;
                m = sv;
            }
            const float w = __expf(sv - m);
            l += w;
            const float* vp = vh + (size_t)kidx*CAC + h*DKD + dh*16;
            #pragma unroll
            for (int jj = 0; jj < 4; ++jj) {
                const float4 vv = *(const float4*)(vp + jj*4);
                acc[jj*4]   = fmaf(w, vv.x, acc[jj*4]);
                acc[jj*4+1] = fmaf(w, vv.y, acc[jj*4+1]);
                acc[jj*4+2] = fmaf(w, vv.z, acc[jj*4+2]);
                acc[jj*4+3] = fmaf(w, vv.w, acc[jj*4+3]);
            }
        }
    }

    const int part = tid & 255;
    if (kh2 == 1) {
        sm_m[part] = m; sm_l[part] = l;
        #pragma unroll
        for (int j = 0; j < 16; ++j) sm_acc[part*17 + j] = acc[j];
    }
    __syncthreads();
    if (kh2 == 0) {
        const float m2 = sm_m[part], l2 = sm_l[part];
        const float mm = fmaxf(m, m2);
        const float c1 = __expf(m - mm), c2 = __expf(m2 - mm);
        const float inv = 1.0f / (l*c1 + l2*c2);
        float* op = oh + (size_t)(n0+q)*CAC + h*DKD + dh*16;
        #pragma unroll
        for (int jj = 0; jj < 4; ++jj) {
            float o0 = (acc[jj*4  ]*c1 + sm_acc[part*17+jj*4  ]*c2) * inv;
            float o1 = (acc[jj*4+1]*c1 + sm_acc[part*17+jj*4+1]*c2) * inv;
            float o2 = (acc[jj*4+2]*c1 + sm_acc[part*17+jj*4+2]*c2) * inv;
            float o3 = (acc[jj*4+3]*c1 + sm_acc[part*17+jj*4+3]*c2) * inv;
            *(float4*)op = make_float4(o0,o1,o2,o3);
            op += 4;
        }
    }
}

// ---------------------------------------------------------------------------
// elementwise kernels (4 elements/thread)
// ---------------------------------------------------------------------------
__global__ __launch_bounds__(256) void k_ada2(
    const float* __restrict__ qa,
    const short* __restrict__ G1, const short* __restrict__ S1,
    const short* __restrict__ G2, const short* __restrict__ S2,
    short* __restrict__ x1, short* __restrict__ x2)
{
    const int i = blockIdx.x*256 + threadIdx.x;
    const float4 a = ((const float4*)qa)[i];
    const s16x4 g1 = ((const s16x4*)G1)[i], s1 = ((const s16x4*)S1)[i];
    const s16x4 g2 = ((const s16x4*)G2)[i], s2 = ((const s16x4*)S2)[i];
    s16x4 o1, o2;
    o1[0] = f2bf(b2f(g1[0])*a.x + b2f(s1[0]));
    o1[1] = f2bf(b2f(g1[1])*a.y + b2f(s1[1]));
    o1[2] = f2bf(b2f(g1[2])*a.z + b2f(s1[2]));
    o1[3] = f2bf(b2f(g1[3])*a.w + b2f(s1[3]));
    o2[0] = f2bf(b2f(g2[0])*a.x + b2f(s2[0]));
    o2[1] = f2bf(b2f(g2[1])*a.y + b2f(s2[1]));
    o2[2] = f2bf(b2f(g2[2])*a.z + b2f(s2[2]));
    o2[3] = f2bf(b2f(g2[3])*a.w + b2f(s2[3]));
    ((s16x4*)x1)[i] = o1;
    ((s16x4*)x2)[i] = o2;
}

__global__ __launch_bounds__(256) void k_ada1(
    const float* __restrict__ qa,
    const short* __restrict__ G1, const short* __restrict__ S1,
    short* __restrict__ x1)
{
    const int i = blockIdx.x*256 + threadIdx.x;
    const float4 a = ((const float4*)qa)[i];
    const s16x4 g1 = ((const s16x4*)G1)[i], s1 = ((const s16x4*)S1)[i];
    s16x4 o1;
    o1[0] = f2bf(b2f(g1[0])*a.x + b2f(s1[0]));
    o1[1] = f2bf(b2f(g1[1])*a.y + b2f(s1[1]));
    o1[2] = f2bf(b2f(g1[2])*a.z + b2f(s1[2]));
    o1[3] = f2bf(b2f(g1[3])*a.w + b2f(s1[3]));
    ((s16x4*)x1)[i] = o1;
}

__global__ __launch_bounds__(256) void k_og(
    const float* __restrict__ o, const float* __restrict__ g, short* __restrict__ og)
{
    const int i = blockIdx.x*256 + threadIdx.x;
    const float4 a = ((const float4*)o)[i];
    const float4 b = ((const float4*)g)[i];
    s16x4 r;
    r[0] = f2bf(a.x*b.x); r[1] = f2bf(a.y*b.y); r[2] = f2bf(a.z*b.z); r[3] = f2bf(a.w*b.w);
    ((s16x4*)og)[i] = r;
}

__global__ __launch_bounds__(256) void k_axpy_g(
    float* __restrict__ y, const float* __restrict__ t,
    const short* __restrict__ g, short* __restrict__ ybf)
{
    const int i = blockIdx.x*256 + threadIdx.x;
    float4 yv = ((const float4*)y)[i];
    const float4 tv = ((const float4*)t)[i];
    const s16x4 gv = ((const s16x4*)g)[i];
    yv.x += tv.x * b2f(gv[0]);
    yv.y += tv.y * b2f(gv[1]);
    yv.z += tv.z * b2f(gv[2]);
    yv.w += tv.w * b2f(gv[3]);
    ((float4*)y)[i] = yv;
    if (ybf) {
        s16x4 r;
        r[0] = f2bf(yv.x); r[1] = f2bf(yv.y); r[2] = f2bf(yv.z); r[3] = f2bf(yv.w);
        ((s16x4*)ybf)[i] = r;
    }
}

__global__ __launch_bounds__(256) void k_silu_bf(
    const float* __restrict__ h1, const float* __restrict__ h2, short* __restrict__ hs)
{
    const int i = blockIdx.x*256 + threadIdx.x;
    const float4 a = ((const float4*)h1)[i];
    const float4 b = ((const float4*)h2)[i];
    s16x4 r;
    r[0] = f2bf(a.x * sig_(a.x) * b.x);
    r[1] = f2bf(a.y * sig_(a.y) * b.y);
    r[2] = f2bf(a.z * sig_(a.z) * b.z);
    r[3] = f2bf(a.w * sig_(a.w) * b.w);
    ((s16x4*)hs)[i] = r;
}

__global__ __launch_bounds__(256) void k_token_reduce(
    const float* __restrict__ tok, const float* __restrict__ msk, float* __restrict__ out)
{
    const int gid = blockIdx.x*256 + threadIdx.x;
    const int t = gid / CTC, c = gid - t*CTC;
    float num = 0.0f, den = 0.0f;
    #pragma unroll
    for (int a = 0; a < AA; ++a) {
        const float mv = msk[t*AA + a];
        num += tok[(size_t)(t*AA+a)*CTC + c] * mv;
        den += mv;
    }
    out[gid] = num / fmaxf(den, 1e-10f);
}

// ---------------------------------------------------------------------------
// launch
// ---------------------------------------------------------------------------
static inline MJob mj(const short* A, const short* Bt, const float* bias,
                      float* outF, short* outB, int K, int ostride, int epi)
{
    MJob j; j.A=A; j.Bt=Bt; j.bias=bias; j.outF=outF; j.outB=outB;
    j.K=K; j.ostride=ostride; j.epi=epi; return j;
}

extern "C" void kernel_launch(void* const* d_in, const int* in_sizes, int n_in,
                              void* d_out, int out_size, void* d_ws, size_t ws_size,
                              hipStream_t stream)
{
    const float* positions = (const float*)d_in[0];
    const float* maskp     = (const float*)d_in[1];
    const int*   element   = (const int*  )d_in[2];
    const float* charge    = (const float*)d_in[3];
    const int*   chars     = (const int*  )d_in[4];
    const int*   uid       = (const int*  )d_in[5];
    const float* w_ref_pos      = (const float*)d_in[6];
    const float* w_ref_mask     = (const float*)d_in[7];
    const float* w_ref_element  = (const float*)d_in[8];
    const float* w_ref_charge   = (const float*)d_in[9];
    const float* w_ref_atom_name= (const float*)d_in[10];
    const float* w_s2p_row      = (const float*)d_in[11];
    const float* w_s2p_col      = (const float*)d_in[12];
    const float* w_pair_offsets = (const float*)d_in[13];
    const float* w_pair_dist    = (const float*)d_in[14];
    const float* w_pair_mask    = (const float*)d_in[15];
    const float* w_pair_mlp1    = (const float*)d_in[16];
    const float* w_pair_mlp2    = (const float*)d_in[17];
    const float* w_pair_mlp3    = (const float*)d_in[18];
    const float* w_pair_ln      = (const float*)d_in[19];
    const float* w_pair_logits  = (const float*)d_in[20];
    const float* aq_lnw = (const float*)d_in[21];
    const float* aq_gw  = (const float*)d_in[22];
    const float* aq_gb  = (const float*)d_in[23];
    const float* aq_sw  = (const float*)d_in[24];
    const float* ak_lnw = (const float*)d_in[25];
    const float* ak_gw  = (const float*)d_in[26];
    const float* ak_gb  = (const float*)d_in[27];
    const float* ak_sw  = (const float*)d_in[28];
    const float* wq     = (const float*)d_in[29];
    const float* bq     = (const float*)d_in[30];
    const float* wk     = (const float*)d_in[31];
    const float* wv     = (const float*)d_in[32];
    const float* wg     = (const float*)d_in[33];
    const float* azi_w  = (const float*)d_in[34];
    const float* azi_cw = (const float*)d_in[35];
    const float* azi_cb = (const float*)d_in[36];
    const float* t_lnw  = (const float*)d_in[37];
    const float* t_gw   = (const float*)d_in[38];
    const float* t_gb   = (const float*)d_in[39];
    const float* t_sw   = (const float*)d_in[40];
    const float* glu1   = (const float*)d_in[41];
    const float* glu2   = (const float*)d_in[42];
    const float* t_azi_w  = (const float*)d_in[43];
    const float* t_azi_cw = (const float*)d_in[44];
    const float* t_azi_cb = (const float*)d_in[45];
    const float* w_project= (const float*)d_in[46];

    float* token_o = (float*)d_out;
    float* qact = token_o + 1572864;
    float* qsc  = token_o + 3670016;
    float* pair = token_o + 5767168;

    // workspace layout (total 178,257,920 B == verified ws floor)
    char* W = (char*)d_ws;
    short* pl_bf   = (short*)(W);                 // 50,331,648
    short* wbf     = (short*)(W + 50331648);      //  2,097,152
    short* qn_bf   = (short*)(W + 52428800);      //  4,194,304
    short* qsc_bf  = (short*)(W + 56623104);      //  4,194,304
    float* qa      = (float*)(W + 60817408);      //  8,388,608
    short* Gq_bf   = (short*)(W + 69206016);
    short* Sq_bf   = (short*)(W + 73400320);
    short* Gk_bf   = (short*)(W + 77594624);
    short* Sk_bf   = (short*)(W + 81788928);
    short* Gt_bf   = (short*)(W + 85983232);
    short* St_bf   = (short*)(W + 90177536);
    short* Ag_bf   = (short*)(W + 94371840);
    short* Tg_bf   = (short*)(W + 98566144);
    short* xq_bf   = (short*)(W + 102760448);
    short* xk_bf   = (short*)(W + 106954752);
    float* w_q     = (float*)(W + 111149056);
    float* w_k     = (float*)(W + 119537664);
    float* w_v     = (float*)(W + 127926272);
    float* w_g     = (float*)(W + 136314880);
    float* w_o     = (float*)(W + 144703488);
    short* og_bf   = (short*)(W + 153092096);
    short* hs_bf   = (short*)(W + 157286400);
    short* qact_bf = (short*)(W + 165675008);
    float* rq      = (float*)(W + 169869312);
    float* rk      = (float*)(W + 174063616);
    float* h1  = w_q;   // [N,256] spans w_q+w_k
    float* h2  = w_v;   // [N,256] spans w_v+w_g
    float* tok = w_q;   // [N,384] spans w_q..w_v

    (void)in_sizes; (void)n_in; (void)out_size; (void)ws_size;

    // wbf offsets (shorts)
    const size_t LSTR = 311296;
    const size_t oGQ=0, oSQ=16384, oGK=32768, oSK=49152, oGT=65536, oST=81920,
                 oWQ=98304, oWK=114688, oWV=131072, oWG=147456, oAZ=163840,
                 oACW=180224, oTCW=196608, oG1=212992, oG2=245760, oTAW=278528;
    const size_t oPROJ = 3*LSTR;

    // ---- weight prep ----
    {
        PTab tab{};
        int e = 0;
        for (int i = 0; i < 3; ++i) {
            short* L = wbf + (size_t)i*LSTR;
            const size_t oM = (size_t)i*CAC*CAC, oV = (size_t)i*CAC, oGL = (size_t)i*CAC*2*CAC;
            tab.e[e++] = {aq_gw+oM,  aq_lnw+oV, L+oGQ,  128, 128};
            tab.e[e++] = {aq_sw+oM,  aq_lnw+oV, L+oSQ,  128, 128};
            tab.e[e++] = {ak_gw+oM,  ak_lnw+oV, L+oGK,  128, 128};
            tab.e[e++] = {ak_sw+oM,  ak_lnw+oV, L+oSK,  128, 128};
            tab.e[e++] = {t_gw+oM,   t_lnw+oV,  L+oGT,  128, 128};
            tab.e[e++] = {t_sw+oM,   t_lnw+oV,  L+oST,  128, 128};
            tab.e[e++] = {wq+oM,     nullptr,   L+oWQ,  128, 128};
            tab.e[e++] = {wk+oM,     nullptr,   L+oWK,  128, 128};
            tab.e[e++] = {wv+oM,     nullptr,   L+oWV,  128, 128};
            tab.e[e++] = {wg+oM,     nullptr,   L+oWG,  128, 128};
            tab.e[e++] = {azi_w+oM,  nullptr,   L+oAZ,  128, 128};
            tab.e[e++] = {azi_cw+oM, nullptr,   L+oACW, 128, 128};
            tab.e[e++] = {t_azi_cw+oM,nullptr,  L+oTCW, 128, 128};
            tab.e[e++] = {glu1+oGL,  nullptr,   L+oG1,  128, 256};
            tab.e[e++] = {glu2+oGL,  nullptr,   L+oG2,  128, 256};
            tab.e[e++] = {t_azi_w+oGL,nullptr,  L+oTAW, 256, 128};
        }
        tab.e[e++] = {w_project, nullptr, wbf+oPROJ, 128, 384};
        k_prep<<<dim3(48, 49), 256, 0, stream>>>(tab);
    }

    k_atom_cond<<<NN, 128, 0, stream>>>(positions, maskp, element, charge, chars,
        w_ref_pos, w_ref_mask, w_ref_element, w_ref_charge, w_ref_atom_name,
        w_s2p_row, w_s2p_col, qsc, qact, qsc_bf, qn_bf, rq, rk);

    k_pair<<<(SS*QBQ*KBK)/256, 256, 0, stream>>>(positions, uid, rq, rk,
        w_pair_offsets, w_pair_dist, w_pair_mask, w_pair_mlp1, w_pair_mlp2, w_pair_mlp3,
        w_pair_ln, w_pair_logits, pair, pl_bf);

    for (int i = 0; i < 3; ++i) {
        short* L = wbf + (size_t)i*LSTR;
        const size_t oV = (size_t)i*CAC;

        k_rowln<<<NN, 128, 0, stream>>>(qact, qa);

        {   // all cond-only GEMMs for this layer (8 jobs)
            MJobs js{};
            js.j[0] = mj(qn_bf,  L+oGQ,  aq_gb+oV,    nullptr, Gq_bf, 128, 128, EPI_SIG);
            js.j[1] = mj(qn_bf,  L+oSQ,  nullptr,     nullptr, Sq_bf, 128, 128, EPI_PLAIN);
            js.j[2] = mj(qn_bf,  L+oGK,  ak_gb+oV,    nullptr, Gk_bf, 128, 128, EPI_SIG);
            js.j[3] = mj(qn_bf,  L+oSK,  nullptr,     nullptr, Sk_bf, 128, 128, EPI_PLAIN);
            js.j[4] = mj(qn_bf,  L+oGT,  t_gb+oV,     nullptr, Gt_bf, 128, 128, EPI_SIG);
            js.j[5] = mj(qn_bf,  L+oST,  nullptr,     nullptr, St_bf, 128, 128, EPI_PLAIN);
            js.j[6] = mj(qsc_bf, L+oACW, azi_cb+oV,   nullptr, Ag_bf, 128, 128, EPI_SIG);
            js.j[7] = mj(qsc_bf, L+oTCW, t_azi_cb+oV, nullptr, Tg_bf, 128, 128, EPI_SIG);
            k_mm<<<dim3(128, 8), 256, 0, stream>>>(js);
        }
        k_ada2<<<2048, 256, 0, stream>>>(qa, Gq_bf, Sq_bf, Gk_bf, Sk_bf, xq_bf, xk_bf);
        {   // q,k,v,g projections
            MJobs js{};
            js.j[0] = mj(xq_bf, L+oWQ, bq+oV,   w_q, nullptr, 128, 128, EPI_PLAIN);
            js.j[1] = mj(xk_bf, L+oWK, nullptr, w_k, nullptr, 128, 128, EPI_PLAIN);
            js.j[2] = mj(xk_bf, L+oWV, nullptr, w_v, nullptr, 128, 128, EPI_PLAIN);
            js.j[3] = mj(xq_bf, L+oWG, nullptr, w_g, nullptr, 128, 128, EPI_SIG);
            k_mm<<<dim3(128, 4), 256, 0, stream>>>(js);
        }
        k_attn2<<<SS, 512, 0, stream>>>(w_q, w_k, w_v, pl_bf + (size_t)i*8388608, w_o);
        k_og<<<2048, 256, 0, stream>>>(w_o, w_g, og_bf);
        {   // o-projection
            MJobs js{};
            js.j[0] = mj(og_bf, L+oAZ, nullptr, w_o, nullptr, 128, 128, EPI_PLAIN);
            k_mm<<<dim3(128, 1), 256, 0, stream>>>(js);
        }
        k_axpy_g<<<2048, 256, 0, stream>>>(qact, w_o, Ag_bf, nullptr);
        k_rowln<<<NN, 128, 0, stream>>>(qact, qa);
        k_ada1<<<2048, 256, 0, stream>>>(qa, Gt_bf, St_bf, xq_bf);
        {   // glu1/glu2 as 128-col slices
            MJobs js{};
            js.j[0] = mj(xq_bf, L+oG1,       nullptr, h1,     nullptr, 128, 256, EPI_PLAIN);
            js.j[1] = mj(xq_bf, L+oG1+16384, nullptr, h1+128, nullptr, 128, 256, EPI_PLAIN);
            js.j[2] = mj(xq_bf, L+oG2,       nullptr, h2,     nullptr, 128, 256, EPI_PLAIN);
            js.j[3] = mj(xq_bf, L+oG2+16384, nullptr, h2+128, nullptr, 128, 256, EPI_PLAIN);
            k_mm<<<dim3(128, 4), 256, 0, stream>>>(js);
        }
        k_silu_bf<<<4096, 256, 0, stream>>>(h1, h2, hs_bf);
        {   // transition out-projection (K=256)
            MJobs js{};
            js.j[0] = mj(hs_bf, L+oTAW, nullptr, w_o, nullptr, 256, 128, EPI_PLAIN);
            k_mm<<<dim3(128, 1), 256, 0, stream>>>(js);
        }
        k_axpy_g<<<2048, 256, 0, stream>>>(qact, w_o, Tg_bf, (i == 2) ? qact_bf : nullptr);
    }

    {   // token projection as three 128-col slices
        MJobs js{};
        js.j[0] = mj(qact_bf, wbf+oPROJ,       nullptr, tok,     nullptr, 128, 384, EPI_RELU);
        js.j[1] = mj(qact_bf, wbf+oPROJ+16384, nullptr, tok+128, nullptr, 128, 384, EPI_RELU);
        js.j[2] = mj(qact_bf, wbf+oPROJ+32768, nullptr, tok+256, nullptr, 128, 384, EPI_RELU);
        k_mm<<<dim3(128, 3), 256, 0, stream>>>(js);
    }
    k_token_reduce<<<(TT*CTC)/256, 256, 0, stream>>>(tok, maskp, token_o);
}

// Round 6
// 943.632 us; speedup vs baseline: 2.2140x; 1.0946x over previous
//
#include <hip/hip_runtime.h>
#include <math.h>

#define TT 4096
#define AA 4
#define NN 16384
#define QBQ 32
#define KBK 128
#define SS 512
#define HH 4
#define DKD 32
#define CAC 128
#define CPC 16
#define CTC 384

#define EPI_PLAIN 0
#define EPI_SIG   1
#define EPI_RELU  3

typedef __attribute__((ext_vector_type(8))) short bf16x8;
typedef __attribute__((ext_vector_type(4))) short s16x4;
typedef __attribute__((ext_vector_type(4))) float f32x4;

__device__ __forceinline__ float sig_(float x) { return 1.0f / (1.0f + __expf(-x)); }
__device__ __forceinline__ short f2bf(float f) {
    unsigned u = __float_as_uint(f);
    unsigned r = (u + 0x7FFFu + ((u >> 16) & 1u)) >> 16;
    return (short)r;
}
__device__ __forceinline__ float b2f(short s) {
    return __uint_as_float(((unsigned)(unsigned short)s) << 16);
}

// ---------------------------------------------------------------------------
// K0: weight prep — fp32 [K][NC] -> bf16 transposed [NC][K], optional
//     per-row (k) scale (folds LN weight into the matrix).
// ---------------------------------------------------------------------------
struct PEnt { const float* src; const float* rs; short* dst; int K; int NC; };
struct PTab { PEnt e[49]; };

__global__ __launch_bounds__(256) void k_prep(PTab tab)
{
    const PEnt e = tab.e[blockIdx.y];
    const int ntx = e.NC >> 5, nty = e.K >> 5, nt = ntx * nty;
    __shared__ float sm[32][33];
    const int lx = threadIdx.x & 31, ly = threadIdx.x >> 5;
    for (int t = blockIdx.x; t < nt; t += gridDim.x) {
        const int ty = t / ntx, tx = t - ty * ntx;
        #pragma unroll
        for (int j = 0; j < 4; ++j) {
            const int k = ty * 32 + ly + j * 8;
            const int n = tx * 32 + lx;
            float v = e.src[(size_t)k * e.NC + n];
            if (e.rs) v *= e.rs[k];
            sm[ly + j * 8][lx] = v;
        }
        __syncthreads();
        #pragma unroll
        for (int j = 0; j < 4; ++j) {
            const int n = tx * 32 + ly + j * 8;
            const int k = ty * 32 + lx;
            e.dst[(size_t)n * e.K + k] = f2bf(sm[lx][ly + j * 8]);
        }
        __syncthreads();
    }
}

// ---------------------------------------------------------------------------
// K1: per-atom conditioning
// ---------------------------------------------------------------------------
__global__ __launch_bounds__(128) void k_atom_cond(
    const float* __restrict__ pos, const float* __restrict__ msk,
    const int* __restrict__ elem, const float* __restrict__ chg,
    const int* __restrict__ chars,
    const float* __restrict__ w_pos, const float* __restrict__ w_msk,
    const float* __restrict__ w_elem, const float* __restrict__ w_chg,
    const float* __restrict__ w_name,
    const float* __restrict__ w_row, const float* __restrict__ w_col,
    float* __restrict__ qsc, float* __restrict__ qact,
    short* __restrict__ qsc_bf, short* __restrict__ qn_bf,
    float* __restrict__ rq, float* __restrict__ rk)
{
    const int n = blockIdx.x, c = threadIdx.x;
    const float p0 = pos[n*3+0], p1 = pos[n*3+1], p2 = pos[n*3+2];
    const float m = msk[n];
    const int   el = elem[n];
    const float ach = asinhf(chg[n]);
    const int c0 = chars[n*4+0], c1 = chars[n*4+1], c2 = chars[n*4+2], c3 = chars[n*4+3];

    float a = p0*w_pos[c] + p1*w_pos[CAC+c] + p2*w_pos[2*CAC+c]
            + m*w_msk[c] + w_elem[el*CAC+c] + ach*w_chg[c]
            + w_name[(c0      )*CAC+c] + w_name[( 64+c1)*CAC+c]
            + w_name[(128+c2)*CAC+c] + w_name[(192+c3)*CAC+c];
    a *= m;

    const size_t base = (size_t)n*CAC + c;
    qsc[base] = a; qact[base] = a; qsc_bf[base] = f2bf(a);

    __shared__ float red[128];
    __shared__ float sh[128];
    red[c] = a; __syncthreads();
    for (int off = 64; off > 0; off >>= 1) { if (c < off) red[c] += red[c+off]; __syncthreads(); }
    const float mu = red[0] * (1.0f/128.0f);
    __syncthreads();
    const float d = a - mu;
    red[c] = d*d; __syncthreads();
    for (int off = 64; off > 0; off >>= 1) { if (c < off) red[c] += red[c+off]; __syncthreads(); }
    const float var = red[0] * (1.0f/128.0f);
    qn_bf[base] = f2bf(d * rsqrtf(var + 1e-5f));
    __syncthreads();
    sh[c] = fmaxf(a, 0.0f);
    __syncthreads();
    if (c < 32) {
        const float* w = (c < 16) ? w_row : w_col;
        const int cc = c & 15;
        float acc = 0.0f;
        #pragma unroll 8
        for (int r = 0; r < 128; ++r) acc += sh[r] * w[r*CPC + cc];
        if (c < 16) rq[(size_t)n*CPC + cc] = acc;
        else        rk[(size_t)n*CPC + cc] = acc;
    }
}

// ---------------------------------------------------------------------------
// K2: pair conditioning + MLP residual; also emits pl (bf16) for all 3 blocks
// ---------------------------------------------------------------------------
__global__ __launch_bounds__(256) void k_pair(
    const float* __restrict__ pos, const int* __restrict__ uid,
    const float* __restrict__ rq, const float* __restrict__ rk,
    const float* __restrict__ w_ofs, const float* __restrict__ w_dist,
    const float* __restrict__ w_pm,
    const float* __restrict__ mlp1, const float* __restrict__ mlp2,
    const float* __restrict__ mlp3,
    const float* __restrict__ wln, const float* __restrict__ wpl,
    float* __restrict__ pair, short* __restrict__ plb)
{
    __shared__ float sm1[256], sm2[256], sm3[256], sofs[48], sdist[16], smask[16];
    __shared__ float swln[16], swpl[192];
    const int tid = threadIdx.x;
    sm1[tid] = mlp1[tid]; sm2[tid] = mlp2[tid]; sm3[tid] = mlp3[tid];
    if (tid < 48) sofs[tid] = w_ofs[tid];
    if (tid < 16) { sdist[tid] = w_dist[tid]; smask[tid] = w_pm[tid]; swln[tid] = wln[tid]; }
    if (tid < 192) swpl[tid] = wpl[tid];
    __syncthreads();

    const int gid = blockIdx.x*256 + tid;
    const int s = gid >> 12;
    const int rem = gid & 4095;
    const int q = rem >> 7, kk = rem & 127;
    const int n = s*QBQ + q;
    int kidx = s*QBQ - 48 + kk; kidx = max(0, min(NN-1, kidx));

    const float v = (uid[n] == uid[kidx]) ? 1.0f : 0.0f;
    const float o0 = pos[n*3+0]-pos[kidx*3+0];
    const float o1 = pos[n*3+1]-pos[kidx*3+1];
    const float o2 = pos[n*3+2]-pos[kidx*3+2];
    const float sq = o0*o0 + o1*o1 + o2*o2;
    const float inv = 1.0f/(1.0f + sq);

    const float* rqp = rq + (size_t)n*CPC;
    const float* rkp = rk + (size_t)kidx*CPC;

    float p[16], t1[16], t2[16];
    #pragma unroll
    for (int j = 0; j < 16; ++j)
        p[j] = v*(o0*sofs[j] + o1*sofs[16+j] + o2*sofs[32+j] + inv*sdist[j] + smask[j])
             + rqp[j] + rkp[j];
    #pragma unroll
    for (int j = 0; j < 16; ++j) {
        float acc = 0.0f;
        #pragma unroll
        for (int r = 0; r < 16; ++r) acc += fmaxf(p[r], 0.0f) * sm1[r*16+j];
        t1[j] = acc;
    }
    #pragma unroll
    for (int j = 0; j < 16; ++j) {
        float acc = 0.0f;
        #pragma unroll
        for (int r = 0; r < 16; ++r) acc += fmaxf(t1[r], 0.0f) * sm2[r*16+j];
        t2[j] = acc;
    }
    #pragma unroll
    for (int j = 0; j < 16; ++j) {
        float acc = 0.0f;
        #pragma unroll
        for (int r = 0; r < 16; ++r) acc += fmaxf(t2[r], 0.0f) * sm3[r*16+j];
        t1[j] = p[j] + acc;
    }
    float* op = pair + (size_t)gid*CPC;
    #pragma unroll
    for (int j = 0; j < 4; ++j)
        *(float4*)(op + j*4) = make_float4(t1[j*4], t1[j*4+1], t1[j*4+2], t1[j*4+3]);

    // LN over 16 channels + projection to 12 logit planes (3 blocks x 4 heads)
    float sm = 0.0f;
    #pragma unroll
    for (int j = 0; j < 16; ++j) sm += t1[j];
    const float mu = sm * (1.0f/16.0f);
    float vq = 0.0f;
    #pragma unroll
    for (int j = 0; j < 16; ++j) { const float dd = t1[j]-mu; vq += dd*dd; }
    const float rs = rsqrtf(vq*(1.0f/16.0f) + 1e-5f);
    float xn[16];
    #pragma unroll
    for (int j = 0; j < 16; ++j) xn[j] = (t1[j]-mu)*rs*swln[j];
    #pragma unroll
    for (int i = 0; i < 3; ++i) {
        #pragma unroll
        for (int h = 0; h < 4; ++h) {
            float acc = 0.0f;
            #pragma unroll
            for (int j = 0; j < 16; ++j) acc += xn[j] * swpl[j*12 + i*4 + h];
            plb[((((size_t)i*SS + s)*HH + h)*QBQ + q)*KBK + kk] = f2bf(acc);
        }
    }
}

// ---------------------------------------------------------------------------
// K3: fused residual + LayerNorm + adaLN-gate apply.
//     a = qact + o*gate (if o) ; qact = a ; ln = LN(a) (if x1)
//     x1 = G1*ln + S1 ; x2 = G2*ln + S2 (if x2) ; ybf = bf16(a) (if ybf)
// ---------------------------------------------------------------------------
__global__ __launch_bounds__(128) void k_resada(
    float* __restrict__ qact, const float* __restrict__ o,
    const short* __restrict__ g,
    const short* __restrict__ G1, const short* __restrict__ S1,
    const short* __restrict__ G2, const short* __restrict__ S2,
    short* __restrict__ x1, short* __restrict__ x2, short* __restrict__ ybf)
{
    const int n = blockIdx.x, c = threadIdx.x;
    const size_t base = (size_t)n*CAC + c;
    float a = qact[base];
    if (o) {
        a += o[base] * b2f(g[base]);
        qact[base] = a;
    }
    if (x1) {
        __shared__ float red[128];
        red[c] = a; __syncthreads();
        for (int off = 64; off > 0; off >>= 1) { if (c < off) red[c] += red[c+off]; __syncthreads(); }
        const float mu = red[0] * (1.0f/128.0f);
        __syncthreads();
        const float d = a - mu;
        red[c] = d*d; __syncthreads();
        for (int off = 64; off > 0; off >>= 1) { if (c < off) red[c] += red[c+off]; __syncthreads(); }
        const float var = red[0] * (1.0f/128.0f);
        const float ln = d * rsqrtf(var + 1e-5f);
        x1[base] = f2bf(b2f(G1[base])*ln + b2f(S1[base]));
        if (x2) x2[base] = f2bf(b2f(G2[base])*ln + b2f(S2[base]));
    }
    if (ybf) ybf[base] = f2bf(a);
}

// ---------------------------------------------------------------------------
// K4: bf16 MFMA multi-job GEMM.  out[16384,128] = A[16384,K]@B[K,128]
//     A: bf16 row-major [M][K].  Bt: bf16 transposed [128][K].
//     Tile 128x128, K_STEP=64, XOR-swizzled LDS, 4 waves x (2x8) 16x16x32.
// ---------------------------------------------------------------------------
struct MJob {
    const short* A; const short* Bt; const float* bias;
    float* outF; short* outB;
    int K; int ostride; int epi;
};
struct MJobs { MJob j[8]; };

__global__ __launch_bounds__(256) void k_mm(MJobs jobs)
{
    __shared__ short As[128*64];
    __shared__ short Bs[128*64];
    const MJob J = jobs.j[blockIdx.y];
    const int tid = threadIdx.x;
    const int wave = tid >> 6, lane = tid & 63;
    const int l15 = lane & 15, l4 = lane >> 4;
    const int row0 = blockIdx.x * 128;
    const int K = J.K;

    f32x4 acc[2][8];
    #pragma unroll
    for (int m = 0; m < 2; ++m)
        #pragma unroll
        for (int n = 0; n < 8; ++n) acc[m][n] = (f32x4){0.f,0.f,0.f,0.f};

    for (int k0 = 0; k0 < K; k0 += 64) {
        #pragma unroll
        for (int j = 0; j < 4; ++j) {
            const int u = tid + j*256;
            const int r = u >> 3, ug = u & 7;
            const bf16x8 av = *(const bf16x8*)(J.A + (size_t)(row0 + r)*K + k0 + ug*8);
            *(bf16x8*)&As[r*64 + ((ug ^ (r & 7)) * 8)] = av;
            const bf16x8 bv = *(const bf16x8*)(J.Bt + (size_t)r*K + k0 + ug*8);
            *(bf16x8*)&Bs[r*64 + ((ug ^ (r & 7)) * 8)] = bv;
        }
        __syncthreads();
        #pragma unroll
        for (int ks = 0; ks < 2; ++ks) {
            bf16x8 af[2], bfr[8];
            #pragma unroll
            for (int m = 0; m < 2; ++m) {
                const int r = wave*32 + m*16 + l15;
                af[m] = *(const bf16x8*)&As[r*64 + (((ks*4 + l4) ^ (r & 7)) * 8)];
            }
            #pragma unroll
            for (int n = 0; n < 8; ++n) {
                const int c = n*16 + l15;
                bfr[n] = *(const bf16x8*)&Bs[c*64 + (((ks*4 + l4) ^ (c & 7)) * 8)];
            }
            #pragma unroll
            for (int m = 0; m < 2; ++m)
                #pragma unroll
                for (int n = 0; n < 8; ++n)
                    acc[m][n] = __builtin_amdgcn_mfma_f32_16x16x32_bf16(af[m], bfr[n], acc[m][n], 0, 0, 0);
        }
        __syncthreads();
    }

    float bval[8];
    #pragma unroll
    for (int n = 0; n < 8; ++n) bval[n] = 0.0f;
    if (J.bias) {
        #pragma unroll
        for (int n = 0; n < 8; ++n) bval[n] = J.bias[n*16 + l15];
    }
    const int epi = J.epi;
    #pragma unroll
    for (int m = 0; m < 2; ++m) {
        #pragma unroll
        for (int n = 0; n < 8; ++n) {
            const int col = n*16 + l15;
            #pragma unroll
            for (int reg = 0; reg < 4; ++reg) {
                const int row = row0 + wave*32 + m*16 + l4*4 + reg;
                float v = acc[m][n][reg] + bval[n];
                if (epi == EPI_SIG)  v = sig_(v);
                if (epi == EPI_RELU) v = fmaxf(v, 0.0f);
                if (J.outB) J.outB[(size_t)row*J.ostride + col] = f2bf(v);
                else        J.outF[(size_t)row*J.ostride + col] = v;
            }
        }
    }
}

// ---------------------------------------------------------------------------
// K4b: o-projection GEMM with fused A = bf16(w_o * w_g).  K=NC=128, fp32 out.
// ---------------------------------------------------------------------------
__global__ __launch_bounds__(256) void k_mm_og(
    const float* __restrict__ Ao, const float* __restrict__ Agt,
    const short* __restrict__ Bt, float* __restrict__ out)
{
    __shared__ short As[128*64];
    __shared__ short Bs[128*64];
    const int tid = threadIdx.x;
    const int wave = tid >> 6, lane = tid & 63;
    const int l15 = lane & 15, l4 = lane >> 4;
    const int row0 = blockIdx.x * 128;

    f32x4 acc[2][8];
    #pragma unroll
    for (int m = 0; m < 2; ++m)
        #pragma unroll
        for (int n = 0; n < 8; ++n) acc[m][n] = (f32x4){0.f,0.f,0.f,0.f};

    for (int k0 = 0; k0 < 128; k0 += 64) {
        #pragma unroll
        for (int j = 0; j < 4; ++j) {
            const int u = tid + j*256;
            const int r = u >> 3, ug = u & 7;
            const size_t ab = (size_t)(row0 + r)*128 + k0 + ug*8;
            const float4 oa = *(const float4*)(Ao + ab);
            const float4 ob = *(const float4*)(Ao + ab + 4);
            const float4 ga = *(const float4*)(Agt + ab);
            const float4 gb = *(const float4*)(Agt + ab + 4);
            bf16x8 av;
            av[0]=f2bf(oa.x*ga.x); av[1]=f2bf(oa.y*ga.y); av[2]=f2bf(oa.z*ga.z); av[3]=f2bf(oa.w*ga.w);
            av[4]=f2bf(ob.x*gb.x); av[5]=f2bf(ob.y*gb.y); av[6]=f2bf(ob.z*gb.z); av[7]=f2bf(ob.w*gb.w);
            *(bf16x8*)&As[r*64 + ((ug ^ (r & 7)) * 8)] = av;
            const bf16x8 bv = *(const bf16x8*)(Bt + (size_t)r*128 + k0 + ug*8);
            *(bf16x8*)&Bs[r*64 + ((ug ^ (r & 7)) * 8)] = bv;
        }
        __syncthreads();
        #pragma unroll
        for (int ks = 0; ks < 2; ++ks) {
            bf16x8 af[2], bfr[8];
            #pragma unroll
            for (int m = 0; m < 2; ++m) {
                const int r = wave*32 + m*16 + l15;
                af[m] = *(const bf16x8*)&As[r*64 + (((ks*4 + l4) ^ (r & 7)) * 8)];
            }
            #pragma unroll
            for (int n = 0; n < 8; ++n) {
                const int c = n*16 + l15;
                bfr[n] = *(const bf16x8*)&Bs[c*64 + (((ks*4 + l4) ^ (c & 7)) * 8)];
            }
            #pragma unroll
            for (int m = 0; m < 2; ++m)
                #pragma unroll
                for (int n = 0; n < 8; ++n)
                    acc[m][n] = __builtin_amdgcn_mfma_f32_16x16x32_bf16(af[m], bfr[n], acc[m][n], 0, 0, 0);
        }
        __syncthreads();
    }

    #pragma unroll
    for (int m = 0; m < 2; ++m)
        #pragma unroll
        for (int n = 0; n < 8; ++n) {
            const int col = n*16 + l15;
            #pragma unroll
            for (int reg = 0; reg < 4; ++reg) {
                const int row = row0 + wave*32 + m*16 + l4*4 + reg;
                out[(size_t)row*128 + col] = acc[m][n][reg];
            }
        }
}

// ---------------------------------------------------------------------------
// K4c: dual-B GEMM with fused SwiGLU: hs = bf16(silu(x@glu1)*(x@glu2)).
//      Tile 128x64, K=128, blockIdx.y = 64-col slice (4 slices).
// ---------------------------------------------------------------------------
__global__ __launch_bounds__(256) void k_mm_glu(
    const short* __restrict__ A, const short* __restrict__ B1t,
    const short* __restrict__ B2t, short* __restrict__ out)
{
    __shared__ short As[128*64];
    __shared__ short B1s[64*64];
    __shared__ short B2s[64*64];
    const int tid = threadIdx.x;
    const int wave = tid >> 6, lane = tid & 63;
    const int l15 = lane & 15, l4 = lane >> 4;
    const int row0 = blockIdx.x * 128;
    const int col0 = blockIdx.y * 64;

    f32x4 acc1[2][4], acc2[2][4];
    #pragma unroll
    for (int m = 0; m < 2; ++m)
        #pragma unroll
        for (int n = 0; n < 4; ++n) {
            acc1[m][n] = (f32x4){0.f,0.f,0.f,0.f};
            acc2[m][n] = (f32x4){0.f,0.f,0.f,0.f};
        }

    for (int k0 = 0; k0 < 128; k0 += 64) {
        #pragma unroll
        for (int j = 0; j < 4; ++j) {
            const int u = tid + j*256;
            const int r = u >> 3, ug = u & 7;
            const bf16x8 av = *(const bf16x8*)(A + (size_t)(row0 + r)*128 + k0 + ug*8);
            *(bf16x8*)&As[r*64 + ((ug ^ (r & 7)) * 8)] = av;
        }
        #pragma unroll
        for (int j = 0; j < 2; ++j) {
            const int u = tid + j*256;
            const int r = u >> 3, ug = u & 7;
            const bf16x8 b1 = *(const bf16x8*)(B1t + (size_t)(col0 + r)*128 + k0 + ug*8);
            *(bf16x8*)&B1s[r*64 + ((ug ^ (r & 7)) * 8)] = b1;
            const bf16x8 b2 = *(const bf16x8*)(B2t + (size_t)(col0 + r)*128 + k0 + ug*8);
            *(bf16x8*)&B2s[r*64 + ((ug ^ (r & 7)) * 8)] = b2;
        }
        __syncthreads();
        #pragma unroll
        for (int ks = 0; ks < 2; ++ks) {
            bf16x8 af[2], bq1[4], bq2[4];
            #pragma unroll
            for (int m = 0; m < 2; ++m) {
                const int r = wave*32 + m*16 + l15;
                af[m] = *(const bf16x8*)&As[r*64 + (((ks*4 + l4) ^ (r & 7)) * 8)];
            }
            #pragma unroll
            for (int n = 0; n < 4; ++n) {
                const int c = n*16 + l15;
                bq1[n] = *(const bf16x8*)&B1s[c*64 + (((ks*4 + l4) ^ (c & 7)) * 8)];
                bq2[n] = *(const bf16x8*)&B2s[c*64 + (((ks*4 + l4) ^ (c & 7)) * 8)];
            }
            #pragma unroll
            for (int m = 0; m < 2; ++m)
                #pragma unroll
                for (int n = 0; n < 4; ++n) {
                    acc1[m][n] = __builtin_amdgcn_mfma_f32_16x16x32_bf16(af[m], bq1[n], acc1[m][n], 0, 0, 0);
                    acc2[m][n] = __builtin_amdgcn_mfma_f32_16x16x32_bf16(af[m], bq2[n], acc2[m][n], 0, 0, 0);
                }
        }
        __syncthreads();
    }

    #pragma unroll
    for (int m = 0; m < 2; ++m)
        #pragma unroll
        for (int n = 0; n < 4; ++n) {
            const int col = col0 + n*16 + l15;
            #pragma unroll
            for (int reg = 0; reg < 4; ++reg) {
                const int row = row0 + wave*32 + m*16 + l4*4 + reg;
                const float a1 = acc1[m][n][reg];
                const float h = a1 * sig_(a1) * acc2[m][n][reg];
                out[(size_t)row*256 + col] = f2bf(h);
            }
        }
}

// ---------------------------------------------------------------------------
// K5: flash attention (pl in bf16)
// ---------------------------------------------------------------------------
__global__ __launch_bounds__(512) void k_attn2(
    const float* __restrict__ qh, const float* __restrict__ kh,
    const float* __restrict__ vh, const short* __restrict__ pls,
    float* __restrict__ oh)
{
    __shared__ float sm_m[256], sm_l[256], sm_acc[256*17];
    const int s = blockIdx.x, tid = threadIdx.x;
    const int kh2 = tid >> 8;
    const int h = (tid >> 6) & 3;
    const int q = (tid >> 1) & 31;
    const int dh = tid & 1;
    const int n0 = s*QBQ;
    const int kbase = n0 - 48 + kh2*64;
    const float SCALE = 0.17677669529663687f;

    float qr[32];
    {
        const float* qp = qh + (size_t)(n0+q)*CAC + h*DKD;
        #pragma unroll
        for (int j = 0; j < 8; ++j) {
            const float4 v4 = *(const float4*)(qp + j*4);
            qr[j*4]=v4.x*SCALE; qr[j*4+1]=v4.y*SCALE; qr[j*4+2]=v4.z*SCALE; qr[j*4+3]=v4.w*SCALE;
        }
    }
    const short* plp = pls + (((size_t)s*HH + h)*QBQ + q)*KBK + kh2*64;

    float m = -1e30f, l = 0.0f;
    float acc[16];
    #pragma unroll
    for (int j = 0; j < 16; ++j) acc[j] = 0.0f;

    for (int kb4 = 0; kb4 < 16; ++kb4) {
        const s16x4 p4 = *(const s16x4*)(plp + kb4*4);
        float pv[4];
        #pragma unroll
        for (int j = 0; j < 4; ++j) pv[j] = b2f(p4[j]);
        #pragma unroll
        for (int j = 0; j < 4; ++j) {
            const int kb = kb4*4 + j;
            int kidx = kbase + kb; kidx = max(0, min(NN-1, kidx));
            const float* kp = kh + (size_t)kidx*CAC + h*DKD;
            float dot = 0.0f;
            #pragma unroll
            for (int jj = 0; jj < 8; ++jj) {
                const float4 kv = *(const float4*)(kp + jj*4);
                dot += qr[jj*4]*kv.x + qr[jj*4+1]*kv.y + qr[jj*4+2]*kv.z + qr[jj*4+3]*kv.w;
            }
            const float sv = dot + pv[j];
            if (sv > m) {
                const float corr = __expf(m - sv);
                l *= corr;
                #pragma unroll
                for (int d = 0; d < 16; ++d) acc[d] *= corr;
                m = sv;
            }
            const float w = __expf(sv - m);
            l += w;
            const float* vp = vh + (size_t)kidx*CAC + h*DKD + dh*16;
            #pragma unroll
            for (int jj = 0; jj < 4; ++jj) {
                const float4 vv = *(const float4*)(vp + jj*4);
                acc[jj*4]   = fmaf(w, vv.x, acc[jj*4]);
                acc[jj*4+1] = fmaf(w, vv.y, acc[jj*4+1]);
                acc[jj*4+2] = fmaf(w, vv.z, acc[jj*4+2]);
                acc[jj*4+3] = fmaf(w, vv.w, acc[jj*4+3]);
            }
        }
    }

    const int part = tid & 255;
    if (kh2 == 1) {
        sm_m[part] = m; sm_l[part] = l;
        #pragma unroll
        for (int j = 0; j < 16; ++j) sm_acc[part*17 + j] = acc[j];
    }
    __syncthreads();
    if (kh2 == 0) {
        const float m2 = sm_m[part], l2 = sm_l[part];
        const float mm = fmaxf(m, m2);
        const float c1 = __expf(m - mm), c2 = __expf(m2 - mm);
        const float inv = 1.0f / (l*c1 + l2*c2);
        float* op = oh + (size_t)(n0+q)*CAC + h*DKD + dh*16;
        #pragma unroll
        for (int jj = 0; jj < 4; ++jj) {
            float o0 = (acc[jj*4  ]*c1 + sm_acc[part*17+jj*4  ]*c2) * inv;
            float o1 = (acc[jj*4+1]*c1 + sm_acc[part*17+jj*4+1]*c2) * inv;
            float o2 = (acc[jj*4+2]*c1 + sm_acc[part*17+jj*4+2]*c2) * inv;
            float o3 = (acc[jj*4+3]*c1 + sm_acc[part*17+jj*4+3]*c2) * inv;
            *(float4*)op = make_float4(o0,o1,o2,o3);
            op += 4;
        }
    }
}

__global__ __launch_bounds__(256) void k_token_reduce(
    const float* __restrict__ tok, const float* __restrict__ msk, float* __restrict__ out)
{
    const int gid = blockIdx.x*256 + threadIdx.x;
    const int t = gid / CTC, c = gid - t*CTC;
    float num = 0.0f, den = 0.0f;
    #pragma unroll
    for (int a = 0; a < AA; ++a) {
        const float mv = msk[t*AA + a];
        num += tok[(size_t)(t*AA+a)*CTC + c] * mv;
        den += mv;
    }
    out[gid] = num / fmaxf(den, 1e-10f);
}

// ---------------------------------------------------------------------------
// launch
// ---------------------------------------------------------------------------
static inline MJob mj(const short* A, const short* Bt, const float* bias,
                      float* outF, short* outB, int K, int ostride, int epi)
{
    MJob j; j.A=A; j.Bt=Bt; j.bias=bias; j.outF=outF; j.outB=outB;
    j.K=K; j.ostride=ostride; j.epi=epi; return j;
}

extern "C" void kernel_launch(void* const* d_in, const int* in_sizes, int n_in,
                              void* d_out, int out_size, void* d_ws, size_t ws_size,
                              hipStream_t stream)
{
    const float* positions = (const float*)d_in[0];
    const float* maskp     = (const float*)d_in[1];
    const int*   element   = (const int*  )d_in[2];
    const float* charge    = (const float*)d_in[3];
    const int*   chars     = (const int*  )d_in[4];
    const int*   uid       = (const int*  )d_in[5];
    const float* w_ref_pos      = (const float*)d_in[6];
    const float* w_ref_mask     = (const float*)d_in[7];
    const float* w_ref_element  = (const float*)d_in[8];
    const float* w_ref_charge   = (const float*)d_in[9];
    const float* w_ref_atom_name= (const float*)d_in[10];
    const float* w_s2p_row      = (const float*)d_in[11];
    const float* w_s2p_col      = (const float*)d_in[12];
    const float* w_pair_offsets = (const float*)d_in[13];
    const float* w_pair_dist    = (const float*)d_in[14];
    const float* w_pair_mask    = (const float*)d_in[15];
    const float* w_pair_mlp1    = (const float*)d_in[16];
    const float* w_pair_mlp2    = (const float*)d_in[17];
    const float* w_pair_mlp3    = (const float*)d_in[18];
    const float* w_pair_ln      = (const float*)d_in[19];
    const float* w_pair_logits  = (const float*)d_in[20];
    const float* aq_lnw = (const float*)d_in[21];
    const float* aq_gw  = (const float*)d_in[22];
    const float* aq_gb  = (const float*)d_in[23];
    const float* aq_sw  = (const float*)d_in[24];
    const float* ak_lnw = (const float*)d_in[25];
    const float* ak_gw  = (const float*)d_in[26];
    const float* ak_gb  = (const float*)d_in[27];
    const float* ak_sw  = (const float*)d_in[28];
    const float* wq     = (const float*)d_in[29];
    const float* bq     = (const float*)d_in[30];
    const float* wk     = (const float*)d_in[31];
    const float* wv     = (const float*)d_in[32];
    const float* wg     = (const float*)d_in[33];
    const float* azi_w  = (const float*)d_in[34];
    const float* azi_cw = (const float*)d_in[35];
    const float* azi_cb = (const float*)d_in[36];
    const float* t_lnw  = (const float*)d_in[37];
    const float* t_gw   = (const float*)d_in[38];
    const float* t_gb   = (const float*)d_in[39];
    const float* t_sw   = (const float*)d_in[40];
    const float* glu1   = (const float*)d_in[41];
    const float* glu2   = (const float*)d_in[42];
    const float* t_azi_w  = (const float*)d_in[43];
    const float* t_azi_cw = (const float*)d_in[44];
    const float* t_azi_cb = (const float*)d_in[45];
    const float* w_project= (const float*)d_in[46];

    float* token_o = (float*)d_out;
    float* qact = token_o + 1572864;
    float* qsc  = token_o + 3670016;
    float* pair = token_o + 5767168;

    // workspace layout (total 178,257,920 B == verified ws floor)
    char* W = (char*)d_ws;
    short* pl_bf   = (short*)(W);                 // 50,331,648
    short* wbf     = (short*)(W + 50331648);      //  2,097,152
    short* qn_bf   = (short*)(W + 52428800);      //  4,194,304
    short* qsc_bf  = (short*)(W + 56623104);      //  4,194,304
    float* w_op    = (float*)(W + 60817408);      //  8,388,608  (o/taw projection out)
    short* Gq_bf   = (short*)(W + 69206016);
    short* Sq_bf   = (short*)(W + 73400320);
    short* Gk_bf   = (short*)(W + 77594624);
    short* Sk_bf   = (short*)(W + 81788928);
    short* Gt_bf   = (short*)(W + 85983232);
    short* St_bf   = (short*)(W + 90177536);
    short* Ag_bf   = (short*)(W + 94371840);
    short* Tg0_bf  = (short*)(W + 98566144);      // Tg double-buffer slot 0
    short* xq_bf   = (short*)(W + 102760448);
    short* xk_bf   = (short*)(W + 106954752);
    float* w_q     = (float*)(W + 111149056);
    float* w_k     = (float*)(W + 119537664);
    float* w_v     = (float*)(W + 127926272);
    float* w_g     = (float*)(W + 136314880);
    float* w_o     = (float*)(W + 144703488);
    short* Tg1_bf  = (short*)(W + 153092096);     // Tg double-buffer slot 1
    short* hs_bf   = (short*)(W + 157286400);
    short* qact_bf = (short*)(W + 165675008);
    float* rq      = (float*)(W + 169869312);
    float* rk      = (float*)(W + 174063616);
    float* tok = w_q;   // [N,384] spans w_q..w_v

    (void)in_sizes; (void)n_in; (void)out_size; (void)ws_size;

    // wbf offsets (shorts)
    const size_t LSTR = 311296;
    const size_t oGQ=0, oSQ=16384, oGK=32768, oSK=49152, oGT=65536, oST=81920,
                 oWQ=98304, oWK=114688, oWV=131072, oWG=147456, oAZ=163840,
                 oACW=180224, oTCW=196608, oG1=212992, oG2=245760, oTAW=278528;
    const size_t oPROJ = 3*LSTR;

    // ---- weight prep ----
    {
        PTab tab{};
        int e = 0;
        for (int i = 0; i < 3; ++i) {
            short* L = wbf + (size_t)i*LSTR;
            const size_t oM = (size_t)i*CAC*CAC, oV = (size_t)i*CAC, oGL = (size_t)i*CAC*2*CAC;
            tab.e[e++] = {aq_gw+oM,  aq_lnw+oV, L+oGQ,  128, 128};
            tab.e[e++] = {aq_sw+oM,  aq_lnw+oV, L+oSQ,  128, 128};
            tab.e[e++] = {ak_gw+oM,  ak_lnw+oV, L+oGK,  128, 128};
            tab.e[e++] = {ak_sw+oM,  ak_lnw+oV, L+oSK,  128, 128};
            tab.e[e++] = {t_gw+oM,   t_lnw+oV,  L+oGT,  128, 128};
            tab.e[e++] = {t_sw+oM,   t_lnw+oV,  L+oST,  128, 128};
            tab.e[e++] = {wq+oM,     nullptr,   L+oWQ,  128, 128};
            tab.e[e++] = {wk+oM,     nullptr,   L+oWK,  128, 128};
            tab.e[e++] = {wv+oM,     nullptr,   L+oWV,  128, 128};
            tab.e[e++] = {wg+oM,     nullptr,   L+oWG,  128, 128};
            tab.e[e++] = {azi_w+oM,  nullptr,   L+oAZ,  128, 128};
            tab.e[e++] = {azi_cw+oM, nullptr,   L+oACW, 128, 128};
            tab.e[e++] = {t_azi_cw+oM,nullptr,  L+oTCW, 128, 128};
            tab.e[e++] = {glu1+oGL,  nullptr,   L+oG1,  128, 256};
            tab.e[e++] = {glu2+oGL,  nullptr,   L+oG2,  128, 256};
            tab.e[e++] = {t_azi_w+oGL,nullptr,  L+oTAW, 256, 128};
        }
        tab.e[e++] = {w_project, nullptr, wbf+oPROJ, 128, 384};
        k_prep<<<dim3(48, 49), 256, 0, stream>>>(tab);
    }

    k_atom_cond<<<NN, 128, 0, stream>>>(positions, maskp, element, charge, chars,
        w_ref_pos, w_ref_mask, w_ref_element, w_ref_charge, w_ref_atom_name,
        w_s2p_row, w_s2p_col, qsc, qact, qsc_bf, qn_bf, rq, rk);

    k_pair<<<(SS*QBQ*KBK)/256, 256, 0, stream>>>(positions, uid, rq, rk,
        w_pair_offsets, w_pair_dist, w_pair_mask, w_pair_mlp1, w_pair_mlp2, w_pair_mlp3,
        w_pair_ln, w_pair_logits, pair, pl_bf);

    for (int i = 0; i < 3; ++i) {
        short* L = wbf + (size_t)i*LSTR;
        const size_t oV = (size_t)i*CAC;
        short* Tg_cur  = (i & 1) ? Tg1_bf : Tg0_bf;
        short* Tg_prev = (i & 1) ? Tg0_bf : Tg1_bf;

        {   // all cond-only GEMMs for this layer (8 jobs)
            MJobs js{};
            js.j[0] = mj(qn_bf,  L+oGQ,  aq_gb+oV,    nullptr, Gq_bf, 128, 128, EPI_SIG);
            js.j[1] = mj(qn_bf,  L+oSQ,  nullptr,     nullptr, Sq_bf, 128, 128, EPI_PLAIN);
            js.j[2] = mj(qn_bf,  L+oGK,  ak_gb+oV,    nullptr, Gk_bf, 128, 128, EPI_SIG);
            js.j[3] = mj(qn_bf,  L+oSK,  nullptr,     nullptr, Sk_bf, 128, 128, EPI_PLAIN);
            js.j[4] = mj(qn_bf,  L+oGT,  t_gb+oV,     nullptr, Gt_bf, 128, 128, EPI_SIG);
            js.j[5] = mj(qn_bf,  L+oST,  nullptr,     nullptr, St_bf, 128, 128, EPI_PLAIN);
            js.j[6] = mj(qsc_bf, L+oACW, azi_cb+oV,   nullptr, Ag_bf, 128, 128, EPI_SIG);
            js.j[7] = mj(qsc_bf, L+oTCW, t_azi_cb+oV, nullptr, Tg_cur, 128, 128, EPI_SIG);
            k_mm<<<dim3(128, 8), 256, 0, stream>>>(js);
        }
        // layer entry: (residual from previous transition) + LN + dual ada gates
        k_resada<<<NN, 128, 0, stream>>>(qact,
            (i > 0) ? w_op : nullptr, (i > 0) ? Tg_prev : nullptr,
            Gq_bf, Sq_bf, Gk_bf, Sk_bf, xq_bf, xk_bf, nullptr);
        {   // q,k,v,g projections
            MJobs js{};
            js.j[0] = mj(xq_bf, L+oWQ, bq+oV,   w_q, nullptr, 128, 128, EPI_PLAIN);
            js.j[1] = mj(xk_bf, L+oWK, nullptr, w_k, nullptr, 128, 128, EPI_PLAIN);
            js.j[2] = mj(xk_bf, L+oWV, nullptr, w_v, nullptr, 128, 128, EPI_PLAIN);
            js.j[3] = mj(xq_bf, L+oWG, nullptr, w_g, nullptr, 128, 128, EPI_SIG);
            k_mm<<<dim3(128, 4), 256, 0, stream>>>(js);
        }
        k_attn2<<<SS, 512, 0, stream>>>(w_q, w_k, w_v, pl_bf + (size_t)i*8388608, w_o);
        // o-projection with fused (o * sigmoid-gate) A-operand
        k_mm_og<<<dim3(128), 256, 0, stream>>>(w_o, w_g, L+oAZ, w_op);
        // attention residual + LN + transition ada gate
        k_resada<<<NN, 128, 0, stream>>>(qact, w_op, Ag_bf,
            Gt_bf, St_bf, nullptr, nullptr, xq_bf, nullptr, nullptr);
        // SwiGLU fused (dual-B GEMM + silu*mul epilogue)
        k_mm_glu<<<dim3(128, 4), 256, 0, stream>>>(xq_bf, L+oG1, L+oG2, hs_bf);
        {   // transition out-projection (K=256)
            MJobs js{};
            js.j[0] = mj(hs_bf, L+oTAW, nullptr, w_op, nullptr, 256, 128, EPI_PLAIN);
            k_mm<<<dim3(128, 1), 256, 0, stream>>>(js);
        }
    }
    // final transition residual (layer 2 used Tg slot 0); also emit qact_bf
    k_resada<<<NN, 128, 0, stream>>>(qact, w_op, Tg0_bf,
        nullptr, nullptr, nullptr, nullptr, nullptr, nullptr, qact_bf);

    {   // token projection as three 128-col slices
        MJobs js{};
        js.j[0] = mj(qact_bf, wbf+oPROJ,       nullptr, tok,     nullptr, 128, 384, EPI_RELU);
        js.j[1] = mj(qact_bf, wbf+oPROJ+16384, nullptr, tok+128, nullptr, 128, 384, EPI_RELU);
        js.j[2] = mj(qact_bf, wbf+oPROJ+32768, nullptr, tok+256, nullptr, 128, 384, EPI_RELU);
        k_mm<<<dim3(128, 3), 256, 0, stream>>>(js);
    }
    k_token_reduce<<<(TT*CTC)/256, 256, 0, stream>>>(tok, maskp, token_o);
}

// Round 7
// 933.901 us; speedup vs baseline: 2.2371x; 1.0104x over previous
//
#include <hip/hip_runtime.h>
#include <math.h>

#define TT 4096
#define AA 4
#define NN 16384
#define QBQ 32
#define KBK 128
#define SS 512
#define HH 4
#define DKD 32
#define CAC 128
#define CPC 16
#define CTC 384

typedef __attribute__((ext_vector_type(8))) short bf16x8;
typedef __attribute__((ext_vector_type(4))) short s16x4;
typedef __attribute__((ext_vector_type(4))) float f32x4;

__device__ __forceinline__ float sig_(float x) { return 1.0f / (1.0f + __expf(-x)); }
__device__ __forceinline__ short f2bf(float f) {
    unsigned u = __float_as_uint(f);
    unsigned r = (u + 0x7FFFu + ((u >> 16) & 1u)) >> 16;
    return (short)r;
}
__device__ __forceinline__ float b2f(short s) {
    return __uint_as_float(((unsigned)(unsigned short)s) << 16);
}

// ---------------------------------------------------------------------------
// K0: weight prep — fp32 [K][NC] -> bf16 transposed [NC][K], optional
//     per-row (k) scale (folds LN weight into the matrix).
// ---------------------------------------------------------------------------
struct PEnt { const float* src; const float* rs; short* dst; int K; int NC; };
struct PTab { PEnt e[49]; };

__global__ __launch_bounds__(256) void k_prep(PTab tab)
{
    const PEnt e = tab.e[blockIdx.y];
    const int ntx = e.NC >> 5, nty = e.K >> 5, nt = ntx * nty;
    __shared__ float sm[32][33];
    const int lx = threadIdx.x & 31, ly = threadIdx.x >> 5;
    for (int t = blockIdx.x; t < nt; t += gridDim.x) {
        const int ty = t / ntx, tx = t - ty * ntx;
        #pragma unroll
        for (int j = 0; j < 4; ++j) {
            const int k = ty * 32 + ly + j * 8;
            const int n = tx * 32 + lx;
            float v = e.src[(size_t)k * e.NC + n];
            if (e.rs) v *= e.rs[k];
            sm[ly + j * 8][lx] = v;
        }
        __syncthreads();
        #pragma unroll
        for (int j = 0; j < 4; ++j) {
            const int n = tx * 32 + ly + j * 8;
            const int k = ty * 32 + lx;
            e.dst[(size_t)n * e.K + k] = f2bf(sm[lx][ly + j * 8]);
        }
        __syncthreads();
    }
}

// ---------------------------------------------------------------------------
// K1: per-atom conditioning (+ LN stats output)
// ---------------------------------------------------------------------------
__global__ __launch_bounds__(128) void k_atom_cond(
    const float* __restrict__ pos, const float* __restrict__ msk,
    const int* __restrict__ elem, const float* __restrict__ chg,
    const int* __restrict__ chars,
    const float* __restrict__ w_pos, const float* __restrict__ w_msk,
    const float* __restrict__ w_elem, const float* __restrict__ w_chg,
    const float* __restrict__ w_name,
    const float* __restrict__ w_row, const float* __restrict__ w_col,
    float* __restrict__ qsc, float* __restrict__ qact,
    short* __restrict__ qsc_bf, short* __restrict__ qn_bf,
    float* __restrict__ stats,
    float* __restrict__ rq, float* __restrict__ rk)
{
    const int n = blockIdx.x, c = threadIdx.x;
    const float p0 = pos[n*3+0], p1 = pos[n*3+1], p2 = pos[n*3+2];
    const float m = msk[n];
    const int   el = elem[n];
    const float ach = asinhf(chg[n]);
    const int c0 = chars[n*4+0], c1 = chars[n*4+1], c2 = chars[n*4+2], c3 = chars[n*4+3];

    float a = p0*w_pos[c] + p1*w_pos[CAC+c] + p2*w_pos[2*CAC+c]
            + m*w_msk[c] + w_elem[el*CAC+c] + ach*w_chg[c]
            + w_name[(c0      )*CAC+c] + w_name[( 64+c1)*CAC+c]
            + w_name[(128+c2)*CAC+c] + w_name[(192+c3)*CAC+c];
    a *= m;

    const size_t base = (size_t)n*CAC + c;
    qsc[base] = a; qact[base] = a; qsc_bf[base] = f2bf(a);

    __shared__ float red[128];
    __shared__ float sh[128];
    red[c] = a; __syncthreads();
    for (int off = 64; off > 0; off >>= 1) { if (c < off) red[c] += red[c+off]; __syncthreads(); }
    const float mu = red[0] * (1.0f/128.0f);
    __syncthreads();
    const float d = a - mu;
    red[c] = d*d; __syncthreads();
    for (int off = 64; off > 0; off >>= 1) { if (c < off) red[c] += red[c+off]; __syncthreads(); }
    const float var = red[0] * (1.0f/128.0f);
    const float rs = rsqrtf(var + 1e-5f);
    qn_bf[base] = f2bf(d * rs);
    if (c == 0) { stats[2*n] = mu; stats[2*n+1] = rs; }
    __syncthreads();
    sh[c] = fmaxf(a, 0.0f);
    __syncthreads();
    if (c < 32) {
        const float* w = (c < 16) ? w_row : w_col;
        const int cc = c & 15;
        float acc = 0.0f;
        #pragma unroll 8
        for (int r = 0; r < 128; ++r) acc += sh[r] * w[r*CPC + cc];
        if (c < 16) rq[(size_t)n*CPC + cc] = acc;
        else        rk[(size_t)n*CPC + cc] = acc;
    }
}

// ---------------------------------------------------------------------------
// K2: pair conditioning + MLP residual; also emits pl (bf16) for all 3 blocks
// ---------------------------------------------------------------------------
__global__ __launch_bounds__(256) void k_pair(
    const float* __restrict__ pos, const int* __restrict__ uid,
    const float* __restrict__ rq, const float* __restrict__ rk,
    const float* __restrict__ w_ofs, const float* __restrict__ w_dist,
    const float* __restrict__ w_pm,
    const float* __restrict__ mlp1, const float* __restrict__ mlp2,
    const float* __restrict__ mlp3,
    const float* __restrict__ wln, const float* __restrict__ wpl,
    float* __restrict__ pair, short* __restrict__ plb)
{
    __shared__ float sm1[256], sm2[256], sm3[256], sofs[48], sdist[16], smask[16];
    __shared__ float swln[16], swpl[192];
    const int tid = threadIdx.x;
    sm1[tid] = mlp1[tid]; sm2[tid] = mlp2[tid]; sm3[tid] = mlp3[tid];
    if (tid < 48) sofs[tid] = w_ofs[tid];
    if (tid < 16) { sdist[tid] = w_dist[tid]; smask[tid] = w_pm[tid]; swln[tid] = wln[tid]; }
    if (tid < 192) swpl[tid] = wpl[tid];
    __syncthreads();

    const int gid = blockIdx.x*256 + tid;
    const int s = gid >> 12;
    const int rem = gid & 4095;
    const int q = rem >> 7, kk = rem & 127;
    const int n = s*QBQ + q;
    int kidx = s*QBQ - 48 + kk; kidx = max(0, min(NN-1, kidx));

    const float v = (uid[n] == uid[kidx]) ? 1.0f : 0.0f;
    const float o0 = pos[n*3+0]-pos[kidx*3+0];
    const float o1 = pos[n*3+1]-pos[kidx*3+1];
    const float o2 = pos[n*3+2]-pos[kidx*3+2];
    const float sq = o0*o0 + o1*o1 + o2*o2;
    const float inv = 1.0f/(1.0f + sq);

    const float* rqp = rq + (size_t)n*CPC;
    const float* rkp = rk + (size_t)kidx*CPC;

    float p[16], t1[16], t2[16];
    #pragma unroll
    for (int j = 0; j < 16; ++j)
        p[j] = v*(o0*sofs[j] + o1*sofs[16+j] + o2*sofs[32+j] + inv*sdist[j] + smask[j])
             + rqp[j] + rkp[j];
    #pragma unroll
    for (int j = 0; j < 16; ++j) {
        float acc = 0.0f;
        #pragma unroll
        for (int r = 0; r < 16; ++r) acc += fmaxf(p[r], 0.0f) * sm1[r*16+j];
        t1[j] = acc;
    }
    #pragma unroll
    for (int j = 0; j < 16; ++j) {
        float acc = 0.0f;
        #pragma unroll
        for (int r = 0; r < 16; ++r) acc += fmaxf(t1[r], 0.0f) * sm2[r*16+j];
        t2[j] = acc;
    }
    #pragma unroll
    for (int j = 0; j < 16; ++j) {
        float acc = 0.0f;
        #pragma unroll
        for (int r = 0; r < 16; ++r) acc += fmaxf(t2[r], 0.0f) * sm3[r*16+j];
        t1[j] = p[j] + acc;
    }
    float* op = pair + (size_t)gid*CPC;
    #pragma unroll
    for (int j = 0; j < 4; ++j)
        *(float4*)(op + j*4) = make_float4(t1[j*4], t1[j*4+1], t1[j*4+2], t1[j*4+3]);

    float sm = 0.0f;
    #pragma unroll
    for (int j = 0; j < 16; ++j) sm += t1[j];
    const float mu = sm * (1.0f/16.0f);
    float vq = 0.0f;
    #pragma unroll
    for (int j = 0; j < 16; ++j) { const float dd = t1[j]-mu; vq += dd*dd; }
    const float rs = rsqrtf(vq*(1.0f/16.0f) + 1e-5f);
    float xn[16];
    #pragma unroll
    for (int j = 0; j < 16; ++j) xn[j] = (t1[j]-mu)*rs*swln[j];
    #pragma unroll
    for (int i = 0; i < 3; ++i) {
        #pragma unroll
        for (int h = 0; h < 4; ++h) {
            float acc = 0.0f;
            #pragma unroll
            for (int j = 0; j < 16; ++j) acc += xn[j] * swpl[j*12 + i*4 + h];
            plb[((((size_t)i*SS + s)*HH + h)*QBQ + q)*KBK + kk] = f2bf(acc);
        }
    }
}

// ---------------------------------------------------------------------------
// K4: fused multi-job bf16 MFMA GEMM. Tile 128x128(cols=NC slice), K_STEP=64.
//   amode 0: A bf16 [M][K]
//   amode 1: A = bf16( G*((qact-mu)*rstd) + S )   (adaLN apply, K=128)
//   amode 2: A = bf16( Ao * Ag )                  (o*gate, K=128)
//   amode 3: A = bf16( fp32 A )                   (cast, stride K)
//   emode 0: out = acc (+bias)   -> outB(bf16) or outF(f32)
//   emode 1: out = sig(acc+bias) -> outB/outF
//   emode 2: out = relu(acc)     -> outB/outF
//   emode 3: resid += acc*gate; write resid; emit per-row LN stats (mu,rstd)
// ---------------------------------------------------------------------------
struct FJob {
    const void* A; const void* A2;
    const float* stats; const short* G; const short* S;
    const short* Bt; const float* bias;
    float* outF; short* outB;
    const short* gate; float* resid; float* ostats;
    int K; int ostride; int amode; int emode;
};
struct FJobs { FJob j[8]; };

__global__ __launch_bounds__(256) void k_mmf(FJobs jobs)
{
    __shared__ short As[128*64];
    __shared__ short Bs[128*64];
    const FJob J = jobs.j[blockIdx.y];
    const int tid = threadIdx.x;
    const int wave = tid >> 6, lane = tid & 63;
    const int l15 = lane & 15, l4 = lane >> 4;
    const int row0 = blockIdx.x * 128;
    const int K = J.K;

    f32x4 acc[2][8];
    #pragma unroll
    for (int m = 0; m < 2; ++m)
        #pragma unroll
        for (int n = 0; n < 8; ++n) acc[m][n] = (f32x4){0.f,0.f,0.f,0.f};

    for (int k0 = 0; k0 < K; k0 += 64) {
        #pragma unroll
        for (int j = 0; j < 4; ++j) {
            const int u = tid + j*256;
            const int r = u >> 3, ug = u & 7;
            const int row = row0 + r;
            const size_t ao = (size_t)row*K + k0 + ug*8;
            bf16x8 av;
            if (J.amode == 0) {
                av = *(const bf16x8*)((const short*)J.A + ao);
            } else if (J.amode == 1) {
                const float* Af = (const float*)J.A;
                const float4 a0 = *(const float4*)(Af + ao);
                const float4 a1 = *(const float4*)(Af + ao + 4);
                const float mu = J.stats[2*row], rs = J.stats[2*row+1];
                const s16x4 g0 = *(const s16x4*)(J.G + ao), g1 = *(const s16x4*)(J.G + ao + 4);
                const s16x4 s0 = *(const s16x4*)(J.S + ao), s1 = *(const s16x4*)(J.S + ao + 4);
                const float x[8] = {a0.x,a0.y,a0.z,a0.w,a1.x,a1.y,a1.z,a1.w};
                #pragma unroll
                for (int t = 0; t < 4; ++t) {
                    av[t]   = f2bf(b2f(g0[t])*((x[t]  -mu)*rs) + b2f(s0[t]));
                    av[t+4] = f2bf(b2f(g1[t])*((x[t+4]-mu)*rs) + b2f(s1[t]));
                }
            } else if (J.amode == 2) {
                const float* Ao = (const float*)J.A;
                const float* Ag = (const float*)J.A2;
                const float4 oa = *(const float4*)(Ao + ao);
                const float4 ob = *(const float4*)(Ao + ao + 4);
                const float4 ga = *(const float4*)(Ag + ao);
                const float4 gb = *(const float4*)(Ag + ao + 4);
                av[0]=f2bf(oa.x*ga.x); av[1]=f2bf(oa.y*ga.y); av[2]=f2bf(oa.z*ga.z); av[3]=f2bf(oa.w*ga.w);
                av[4]=f2bf(ob.x*gb.x); av[5]=f2bf(ob.y*gb.y); av[6]=f2bf(ob.z*gb.z); av[7]=f2bf(ob.w*gb.w);
            } else {
                const float* Af = (const float*)J.A;
                const float4 a0 = *(const float4*)(Af + ao);
                const float4 a1 = *(const float4*)(Af + ao + 4);
                av[0]=f2bf(a0.x); av[1]=f2bf(a0.y); av[2]=f2bf(a0.z); av[3]=f2bf(a0.w);
                av[4]=f2bf(a1.x); av[5]=f2bf(a1.y); av[6]=f2bf(a1.z); av[7]=f2bf(a1.w);
            }
            *(bf16x8*)&As[r*64 + ((ug ^ (r & 7)) * 8)] = av;
            const bf16x8 bv = *(const bf16x8*)(J.Bt + (size_t)r*K + k0 + ug*8);
            *(bf16x8*)&Bs[r*64 + ((ug ^ (r & 7)) * 8)] = bv;
        }
        __syncthreads();
        #pragma unroll
        for (int ks = 0; ks < 2; ++ks) {
            bf16x8 af[2], bfr[8];
            #pragma unroll
            for (int m = 0; m < 2; ++m) {
                const int r = wave*32 + m*16 + l15;
                af[m] = *(const bf16x8*)&As[r*64 + (((ks*4 + l4) ^ (r & 7)) * 8)];
            }
            #pragma unroll
            for (int n = 0; n < 8; ++n) {
                const int c = n*16 + l15;
                bfr[n] = *(const bf16x8*)&Bs[c*64 + (((ks*4 + l4) ^ (c & 7)) * 8)];
            }
            #pragma unroll
            for (int m = 0; m < 2; ++m)
                #pragma unroll
                for (int n = 0; n < 8; ++n)
                    acc[m][n] = __builtin_amdgcn_mfma_f32_16x16x32_bf16(af[m], bfr[n], acc[m][n], 0, 0, 0);
        }
        __syncthreads();
    }

    if (J.emode == 3) {
        #pragma unroll
        for (int m = 0; m < 2; ++m) {
            #pragma unroll
            for (int reg = 0; reg < 4; ++reg) {
                const int row = row0 + wave*32 + m*16 + l4*4 + reg;
                float s = 0.0f, q = 0.0f;
                #pragma unroll
                for (int n = 0; n < 8; ++n) {
                    const int col = n*16 + l15;
                    const size_t off = (size_t)row*CAC + col;
                    const float v = J.resid[off] + acc[m][n][reg] * b2f(J.gate[off]);
                    J.resid[off] = v;
                    s += v; q += v*v;
                }
                #pragma unroll
                for (int msk = 1; msk < 16; msk <<= 1) {
                    s += __shfl_xor(s, msk, 64);
                    q += __shfl_xor(q, msk, 64);
                }
                if (l15 == 0) {
                    const float mu = s * (1.0f/128.0f);
                    const float var = q * (1.0f/128.0f) - mu*mu;
                    J.ostats[2*row]   = mu;
                    J.ostats[2*row+1] = rsqrtf(var + 1e-5f);
                }
            }
        }
    } else {
        float bval[8];
        #pragma unroll
        for (int n = 0; n < 8; ++n) bval[n] = 0.0f;
        if (J.bias) {
            #pragma unroll
            for (int n = 0; n < 8; ++n) bval[n] = J.bias[n*16 + l15];
        }
        const int epi = J.emode;
        #pragma unroll
        for (int m = 0; m < 2; ++m) {
            #pragma unroll
            for (int n = 0; n < 8; ++n) {
                const int col = n*16 + l15;
                #pragma unroll
                for (int reg = 0; reg < 4; ++reg) {
                    const int row = row0 + wave*32 + m*16 + l4*4 + reg;
                    float v = acc[m][n][reg] + bval[n];
                    if (epi == 1) v = sig_(v);
                    if (epi == 2) v = fmaxf(v, 0.0f);
                    if (J.outB) J.outB[(size_t)row*J.ostride + col] = f2bf(v);
                    else        J.outF[(size_t)row*J.ostride + col] = v;
                }
            }
        }
    }
}

// ---------------------------------------------------------------------------
// K4c: SwiGLU GEMM with fused adaLN A-staging:
//      x = bf16(Gt*ln(qact)+St); hs = bf16(silu(x@glu1)*(x@glu2)).
//      Tile 128x64, K=128, blockIdx.y = 64-col slice (4 slices).
// ---------------------------------------------------------------------------
__global__ __launch_bounds__(256) void k_mm_glu(
    const float* __restrict__ qact, const float* __restrict__ stats,
    const short* __restrict__ Gt, const short* __restrict__ St,
    const short* __restrict__ B1t, const short* __restrict__ B2t,
    short* __restrict__ out)
{
    __shared__ short As[128*64];
    __shared__ short B1s[64*64];
    __shared__ short B2s[64*64];
    const int tid = threadIdx.x;
    const int wave = tid >> 6, lane = tid & 63;
    const int l15 = lane & 15, l4 = lane >> 4;
    const int row0 = blockIdx.x * 128;
    const int col0 = blockIdx.y * 64;

    f32x4 acc1[2][4], acc2[2][4];
    #pragma unroll
    for (int m = 0; m < 2; ++m)
        #pragma unroll
        for (int n = 0; n < 4; ++n) {
            acc1[m][n] = (f32x4){0.f,0.f,0.f,0.f};
            acc2[m][n] = (f32x4){0.f,0.f,0.f,0.f};
        }

    for (int k0 = 0; k0 < 128; k0 += 64) {
        #pragma unroll
        for (int j = 0; j < 4; ++j) {
            const int u = tid + j*256;
            const int r = u >> 3, ug = u & 7;
            const int row = row0 + r;
            const size_t ao = (size_t)row*CAC + k0 + ug*8;
            const float4 a0 = *(const float4*)(qact + ao);
            const float4 a1 = *(const float4*)(qact + ao + 4);
            const float mu = stats[2*row], rs = stats[2*row+1];
            const s16x4 g0 = *(const s16x4*)(Gt + ao), g1 = *(const s16x4*)(Gt + ao + 4);
            const s16x4 s0 = *(const s16x4*)(St + ao), s1 = *(const s16x4*)(St + ao + 4);
            const float x[8] = {a0.x,a0.y,a0.z,a0.w,a1.x,a1.y,a1.z,a1.w};
            bf16x8 av;
            #pragma unroll
            for (int t = 0; t < 4; ++t) {
                av[t]   = f2bf(b2f(g0[t])*((x[t]  -mu)*rs) + b2f(s0[t]));
                av[t+4] = f2bf(b2f(g1[t])*((x[t+4]-mu)*rs) + b2f(s1[t]));
            }
            *(bf16x8*)&As[r*64 + ((ug ^ (r & 7)) * 8)] = av;
        }
        #pragma unroll
        for (int j = 0; j < 2; ++j) {
            const int u = tid + j*256;
            const int r = u >> 3, ug = u & 7;
            const bf16x8 b1 = *(const bf16x8*)(B1t + (size_t)(col0 + r)*128 + k0 + ug*8);
            *(bf16x8*)&B1s[r*64 + ((ug ^ (r & 7)) * 8)] = b1;
            const bf16x8 b2 = *(const bf16x8*)(B2t + (size_t)(col0 + r)*128 + k0 + ug*8);
            *(bf16x8*)&B2s[r*64 + ((ug ^ (r & 7)) * 8)] = b2;
        }
        __syncthreads();
        #pragma unroll
        for (int ks = 0; ks < 2; ++ks) {
            bf16x8 af[2], bq1[4], bq2[4];
            #pragma unroll
            for (int m = 0; m < 2; ++m) {
                const int r = wave*32 + m*16 + l15;
                af[m] = *(const bf16x8*)&As[r*64 + (((ks*4 + l4) ^ (r & 7)) * 8)];
            }
            #pragma unroll
            for (int n = 0; n < 4; ++n) {
                const int c = n*16 + l15;
                bq1[n] = *(const bf16x8*)&B1s[c*64 + (((ks*4 + l4) ^ (c & 7)) * 8)];
                bq2[n] = *(const bf16x8*)&B2s[c*64 + (((ks*4 + l4) ^ (c & 7)) * 8)];
            }
            #pragma unroll
            for (int m = 0; m < 2; ++m)
                #pragma unroll
                for (int n = 0; n < 4; ++n) {
                    acc1[m][n] = __builtin_amdgcn_mfma_f32_16x16x32_bf16(af[m], bq1[n], acc1[m][n], 0, 0, 0);
                    acc2[m][n] = __builtin_amdgcn_mfma_f32_16x16x32_bf16(af[m], bq2[n], acc2[m][n], 0, 0, 0);
                }
        }
        __syncthreads();
    }

    #pragma unroll
    for (int m = 0; m < 2; ++m)
        #pragma unroll
        for (int n = 0; n < 4; ++n) {
            const int col = col0 + n*16 + l15;
            #pragma unroll
            for (int reg = 0; reg < 4; ++reg) {
                const int row = row0 + wave*32 + m*16 + l4*4 + reg;
                const float a1 = acc1[m][n][reg];
                const float h = a1 * sig_(a1) * acc2[m][n][reg];
                out[(size_t)row*256 + col] = f2bf(h);
            }
        }
}

// ---------------------------------------------------------------------------
// K5: flash attention (pl in bf16)
// ---------------------------------------------------------------------------
__global__ __launch_bounds__(512) void k_attn2(
    const float* __restrict__ qh, const float* __restrict__ kh,
    const float* __restrict__ vh, const short* __restrict__ pls,
    float* __restrict__ oh)
{
    __shared__ float sm_m[256], sm_l[256], sm_acc[256*17];
    const int s = blockIdx.x, tid = threadIdx.x;
    const int kh2 = tid >> 8;
    const int h = (tid >> 6) & 3;
    const int q = (tid >> 1) & 31;
    const int dh = tid & 1;
    const int n0 = s*QBQ;
    const int kbase = n0 - 48 + kh2*64;
    const float SCALE = 0.17677669529663687f;

    float qr[32];
    {
        const float* qp = qh + (size_t)(n0+q)*CAC + h*DKD;
        #pragma unroll
        for (int j = 0; j < 8; ++j) {
            const float4 v4 = *(const float4*)(qp + j*4);
            qr[j*4]=v4.x*SCALE; qr[j*4+1]=v4.y*SCALE; qr[j*4+2]=v4.z*SCALE; qr[j*4+3]=v4.w*SCALE;
        }
    }
    const short* plp = pls + (((size_t)s*HH + h)*QBQ + q)*KBK + kh2*64;

    float m = -1e30f, l = 0.0f;
    float acc[16];
    #pragma unroll
    for (int j = 0; j < 16; ++j) acc[j] = 0.0f;

    for (int kb4 = 0; kb4 < 16; ++kb4) {
        const s16x4 p4 = *(const s16x4*)(plp + kb4*4);
        float pv[4];
        #pragma unroll
        for (int j = 0; j < 4; ++j) pv[j] = b2f(p4[j]);
        #pragma unroll
        for (int j = 0; j < 4; ++j) {
            const int kb = kb4*4 + j;
            int kidx = kbase + kb; kidx = max(0, min(NN-1, kidx));
            const float* kp = kh + (size_t)kidx*CAC + h*DKD;
            float dot = 0.0f;
            #pragma unroll
            for (int jj = 0; jj < 8; ++jj) {
                const float4 kv = *(const float4*)(kp + jj*4);
                dot += qr[jj*4]*kv.x + qr[jj*4+1]*kv.y + qr[jj*4+2]*kv.z + qr[jj*4+3]*kv.w;
            }
            const float sv = dot + pv[j];
            if (sv > m) {
                const float corr = __expf(m - sv);
                l *= corr;
                #pragma unroll
                for (int d = 0; d < 16; ++d) acc[d] *= corr;
                m = sv;
            }
            const float w = __expf(sv - m);
            l += w;
            const float* vp = vh + (size_t)kidx*CAC + h*DKD + dh*16;
            #pragma unroll
            for (int jj = 0; jj < 4; ++jj) {
                const float4 vv = *(const float4*)(vp + jj*4);
                acc[jj*4]   = fmaf(w, vv.x, acc[jj*4]);
                acc[jj*4+1] = fmaf(w, vv.y, acc[jj*4+1]);
                acc[jj*4+2] = fmaf(w, vv.z, acc[jj*4+2]);
                acc[jj*4+3] = fmaf(w, vv.w, acc[jj*4+3]);
            }
        }
    }

    const int part = tid & 255;
    if (kh2 == 1) {
        sm_m[part] = m; sm_l[part] = l;
        #pragma unroll
        for (int j = 0; j < 16; ++j) sm_acc[part*17 + j] = acc[j];
    }
    __syncthreads();
    if (kh2 == 0) {
        const float m2 = sm_m[part], l2 = sm_l[part];
        const float mm = fmaxf(m, m2);
        const float c1 = __expf(m - mm), c2 = __expf(m2 - mm);
        const float inv = 1.0f / (l*c1 + l2*c2);
        float* op = oh + (size_t)(n0+q)*CAC + h*DKD + dh*16;
        #pragma unroll
        for (int jj = 0; jj < 4; ++jj) {
            float o0 = (acc[jj*4  ]*c1 + sm_acc[part*17+jj*4  ]*c2) * inv;
            float o1 = (acc[jj*4+1]*c1 + sm_acc[part*17+jj*4+1]*c2) * inv;
            float o2 = (acc[jj*4+2]*c1 + sm_acc[part*17+jj*4+2]*c2) * inv;
            float o3 = (acc[jj*4+3]*c1 + sm_acc[part*17+jj*4+3]*c2) * inv;
            *(float4*)op = make_float4(o0,o1,o2,o3);
            op += 4;
        }
    }
}

__global__ __launch_bounds__(256) void k_token_reduce(
    const float* __restrict__ tok, const float* __restrict__ msk, float* __restrict__ out)
{
    const int gid = blockIdx.x*256 + threadIdx.x;
    const int t = gid / CTC, c = gid - t*CTC;
    float num = 0.0f, den = 0.0f;
    #pragma unroll
    for (int a = 0; a < AA; ++a) {
        const float mv = msk[t*AA + a];
        num += tok[(size_t)(t*AA+a)*CTC + c] * mv;
        den += mv;
    }
    out[gid] = num / fmaxf(den, 1e-10f);
}

// ---------------------------------------------------------------------------
// launch
// ---------------------------------------------------------------------------
static inline FJob fj0() { FJob j{}; return j; }

extern "C" void kernel_launch(void* const* d_in, const int* in_sizes, int n_in,
                              void* d_out, int out_size, void* d_ws, size_t ws_size,
                              hipStream_t stream)
{
    const float* positions = (const float*)d_in[0];
    const float* maskp     = (const float*)d_in[1];
    const int*   element   = (const int*  )d_in[2];
    const float* charge    = (const float*)d_in[3];
    const int*   chars     = (const int*  )d_in[4];
    const int*   uid       = (const int*  )d_in[5];
    const float* w_ref_pos      = (const float*)d_in[6];
    const float* w_ref_mask     = (const float*)d_in[7];
    const float* w_ref_element  = (const float*)d_in[8];
    const float* w_ref_charge   = (const float*)d_in[9];
    const float* w_ref_atom_name= (const float*)d_in[10];
    const float* w_s2p_row      = (const float*)d_in[11];
    const float* w_s2p_col      = (const float*)d_in[12];
    const float* w_pair_offsets = (const float*)d_in[13];
    const float* w_pair_dist    = (const float*)d_in[14];
    const float* w_pair_mask    = (const float*)d_in[15];
    const float* w_pair_mlp1    = (const float*)d_in[16];
    const float* w_pair_mlp2    = (const float*)d_in[17];
    const float* w_pair_mlp3    = (const float*)d_in[18];
    const float* w_pair_ln      = (const float*)d_in[19];
    const float* w_pair_logits  = (const float*)d_in[20];
    const float* aq_lnw = (const float*)d_in[21];
    const float* aq_gw  = (const float*)d_in[22];
    const float* aq_gb  = (const float*)d_in[23];
    const float* aq_sw  = (const float*)d_in[24];
    const float* ak_lnw = (const float*)d_in[25];
    const float* ak_gw  = (const float*)d_in[26];
    const float* ak_gb  = (const float*)d_in[27];
    const float* ak_sw  = (const float*)d_in[28];
    const float* wq     = (const float*)d_in[29];
    const float* bq     = (const float*)d_in[30];
    const float* wk     = (const float*)d_in[31];
    const float* wv     = (const float*)d_in[32];
    const float* wg     = (const float*)d_in[33];
    const float* azi_w  = (const float*)d_in[34];
    const float* azi_cw = (const float*)d_in[35];
    const float* azi_cb = (const float*)d_in[36];
    const float* t_lnw  = (const float*)d_in[37];
    const float* t_gw   = (const float*)d_in[38];
    const float* t_gb   = (const float*)d_in[39];
    const float* t_sw   = (const float*)d_in[40];
    const float* glu1   = (const float*)d_in[41];
    const float* glu2   = (const float*)d_in[42];
    const float* t_azi_w  = (const float*)d_in[43];
    const float* t_azi_cw = (const float*)d_in[44];
    const float* t_azi_cb = (const float*)d_in[45];
    const float* w_project= (const float*)d_in[46];

    float* token_o = (float*)d_out;
    float* qact = token_o + 1572864;
    float* qsc  = token_o + 3670016;
    float* pair = token_o + 5767168;

    // workspace layout (147 MB used; verified floor is 178 MB)
    char* W = (char*)d_ws;
    short* pl_bf   = (short*)(W);                 // 50,331,648
    short* wbf     = (short*)(W + 50331648);      //  2,097,152
    short* qn_bf   = (short*)(W + 52428800);      //  4,194,304
    short* qsc_bf  = (short*)(W + 56623104);      //  4,194,304
    float* stats   = (float*)(W + 60817408);      //    131,072
    short* Gq_bf   = (short*)(W + 60948480);
    short* Sq_bf   = (short*)(W + 65142784);
    short* Gk_bf   = (short*)(W + 69337088);
    short* Sk_bf   = (short*)(W + 73531392);
    short* Gt_bf   = (short*)(W + 77725696);
    short* St_bf   = (short*)(W + 81920000);
    short* Ag_bf   = (short*)(W + 86114304);
    short* Tg_bf   = (short*)(W + 90308608);
    float* w_q     = (float*)(W + 94502912);      // 8,388,608 each
    float* w_k     = (float*)(W + 102891520);
    float* w_v     = (float*)(W + 111280128);
    float* w_g     = (float*)(W + 119668736);
    float* w_o     = (float*)(W + 128057344);
    short* hs_bf   = (short*)(W + 136445952);     // 8,388,608
    float* rq      = (float*)(W + 144834560);     // 1,048,576
    float* rk      = (float*)(W + 145883136);     // 1,048,576
    float* tok = w_q;   // [N,384] fp32 spans w_q..w_v exactly

    (void)in_sizes; (void)n_in; (void)out_size; (void)ws_size;

    // wbf offsets (shorts)
    const size_t LSTR = 311296;
    const size_t oGQ=0, oSQ=16384, oGK=32768, oSK=49152, oGT=65536, oST=81920,
                 oWQ=98304, oWK=114688, oWV=131072, oWG=147456, oAZ=163840,
                 oACW=180224, oTCW=196608, oG1=212992, oG2=245760, oTAW=278528;
    const size_t oPROJ = 3*LSTR;

    {   // ---- weight prep ----
        PTab tab{};
        int e = 0;
        for (int i = 0; i < 3; ++i) {
            short* L = wbf + (size_t)i*LSTR;
            const size_t oM = (size_t)i*CAC*CAC, oV = (size_t)i*CAC, oGL = (size_t)i*CAC*2*CAC;
            tab.e[e++] = {aq_gw+oM,  aq_lnw+oV, L+oGQ,  128, 128};
            tab.e[e++] = {aq_sw+oM,  aq_lnw+oV, L+oSQ,  128, 128};
            tab.e[e++] = {ak_gw+oM,  ak_lnw+oV, L+oGK,  128, 128};
            tab.e[e++] = {ak_sw+oM,  ak_lnw+oV, L+oSK,  128, 128};
            tab.e[e++] = {t_gw+oM,   t_lnw+oV,  L+oGT,  128, 128};
            tab.e[e++] = {t_sw+oM,   t_lnw+oV,  L+oST,  128, 128};
            tab.e[e++] = {wq+oM,     nullptr,   L+oWQ,  128, 128};
            tab.e[e++] = {wk+oM,     nullptr,   L+oWK,  128, 128};
            tab.e[e++] = {wv+oM,     nullptr,   L+oWV,  128, 128};
            tab.e[e++] = {wg+oM,     nullptr,   L+oWG,  128, 128};
            tab.e[e++] = {azi_w+oM,  nullptr,   L+oAZ,  128, 128};
            tab.e[e++] = {azi_cw+oM, nullptr,   L+oACW, 128, 128};
            tab.e[e++] = {t_azi_cw+oM,nullptr,  L+oTCW, 128, 128};
            tab.e[e++] = {glu1+oGL,  nullptr,   L+oG1,  128, 256};
            tab.e[e++] = {glu2+oGL,  nullptr,   L+oG2,  128, 256};
            tab.e[e++] = {t_azi_w+oGL,nullptr,  L+oTAW, 256, 128};
        }
        tab.e[e++] = {w_project, nullptr, wbf+oPROJ, 128, 384};
        k_prep<<<dim3(48, 49), 256, 0, stream>>>(tab);
    }

    k_atom_cond<<<NN, 128, 0, stream>>>(positions, maskp, element, charge, chars,
        w_ref_pos, w_ref_mask, w_ref_element, w_ref_charge, w_ref_atom_name,
        w_s2p_row, w_s2p_col, qsc, qact, qsc_bf, qn_bf, stats, rq, rk);

    k_pair<<<(SS*QBQ*KBK)/256, 256, 0, stream>>>(positions, uid, rq, rk,
        w_pair_offsets, w_pair_dist, w_pair_mask, w_pair_mlp1, w_pair_mlp2, w_pair_mlp3,
        w_pair_ln, w_pair_logits, pair, pl_bf);

    for (int i = 0; i < 3; ++i) {
        short* L = wbf + (size_t)i*LSTR;
        const size_t oV = (size_t)i*CAC;

        {   // cond-only GEMMs (8 jobs, amode0): gates for this layer
            FJobs js{};
            struct { const short* A; const short* Bt; const float* bias; short* out; int em; } cfg[8] = {
                {qn_bf,  L+oGQ,  aq_gb+oV,    Gq_bf, 1}, {qn_bf,  L+oSQ,  nullptr, Sq_bf, 0},
                {qn_bf,  L+oGK,  ak_gb+oV,    Gk_bf, 1}, {qn_bf,  L+oSK,  nullptr, Sk_bf, 0},
                {qn_bf,  L+oGT,  t_gb+oV,     Gt_bf, 1}, {qn_bf,  L+oST,  nullptr, St_bf, 0},
                {qsc_bf, L+oACW, azi_cb+oV,   Ag_bf, 1}, {qsc_bf, L+oTCW, t_azi_cb+oV, Tg_bf, 1}};
            for (int jn = 0; jn < 8; ++jn) {
                FJob j = fj0();
                j.A = cfg[jn].A; j.Bt = cfg[jn].Bt; j.bias = cfg[jn].bias;
                j.outB = cfg[jn].out; j.K = 128; j.ostride = 128;
                j.amode = 0; j.emode = cfg[jn].em;
                js.j[jn] = j;
            }
            k_mmf<<<dim3(128, 8), 256, 0, stream>>>(js);
        }
        {   // q,k,v,g projections with fused adaLN A-staging (amode1)
            FJobs js{};
            struct { const short* G; const short* S; const short* Bt; const float* bias; float* out; int em; } cfg[4] = {
                {Gq_bf, Sq_bf, L+oWQ, bq+oV,   w_q, 0}, {Gk_bf, Sk_bf, L+oWK, nullptr, w_k, 0},
                {Gk_bf, Sk_bf, L+oWV, nullptr, w_v, 0}, {Gq_bf, Sq_bf, L+oWG, nullptr, w_g, 1}};
            for (int jn = 0; jn < 4; ++jn) {
                FJob j = fj0();
                j.A = qact; j.stats = stats; j.G = cfg[jn].G; j.S = cfg[jn].S;
                j.Bt = cfg[jn].Bt; j.bias = cfg[jn].bias; j.outF = cfg[jn].out;
                j.K = 128; j.ostride = 128; j.amode = 1; j.emode = cfg[jn].em;
                js.j[jn] = j;
            }
            k_mmf<<<dim3(128, 4), 256, 0, stream>>>(js);
        }
        k_attn2<<<SS, 512, 0, stream>>>(w_q, w_k, w_v, pl_bf + (size_t)i*8388608, w_o);
        {   // o-projection: A=o*g fused (amode2); epilogue residual+stats (emode3)
            FJobs js{};
            FJob j = fj0();
            j.A = w_o; j.A2 = w_g; j.Bt = L+oAZ;
            j.gate = Ag_bf; j.resid = qact; j.ostats = stats;
            j.K = 128; j.ostride = 128; j.amode = 2; j.emode = 3;
            js.j[0] = j;
            k_mmf<<<dim3(128, 1), 256, 0, stream>>>(js);
        }
        // SwiGLU (fused adaLN staging + silu*mul epilogue)
        k_mm_glu<<<dim3(128, 4), 256, 0, stream>>>(qact, stats, Gt_bf, St_bf, L+oG1, L+oG2, hs_bf);
        {   // transition out-projection (K=256); epilogue residual+stats
            FJobs js{};
            FJob j = fj0();
            j.A = hs_bf; j.Bt = L+oTAW;
            j.gate = Tg_bf; j.resid = qact; j.ostats = stats;
            j.K = 256; j.ostride = 128; j.amode = 0; j.emode = 3;
            js.j[0] = j;
            k_mmf<<<dim3(128, 1), 256, 0, stream>>>(js);
        }
    }

    {   // token projection: A = fp32 qact cast inline (amode3), 3 col slices
        FJobs js{};
        for (int c = 0; c < 3; ++c) {
            FJob j = fj0();
            j.A = qact; j.Bt = wbf + oPROJ + (size_t)c*16384;
            j.outF = tok + c*128;
            j.K = 128; j.ostride = 384; j.amode = 3; j.emode = 2;
            js.j[c] = j;
        }
        k_mmf<<<dim3(128, 3), 256, 0, stream>>>(js);
    }
    k_token_reduce<<<(TT*CTC)/256, 256, 0, stream>>>(tok, maskp, token_o);
}